// Round 7
// baseline (3957.986 us; speedup 1.0000x reference)
//
#include <hip/hip_runtime.h>
#include <math.h>

#define NDOF 4
#define NB   512
#define NT   64
#define ND   256
#define NS   1024           // NDOF*ND

// 128 blocks = 4 rt (128-row batch tiles) x 32 nt (128 n'-cols).
#define NRT  4
#define GRID (NRT * 32)

typedef __attribute__((ext_vector_type(8))) __bf16 bf16x8;
typedef __attribute__((ext_vector_type(4))) float  f32x4;

// cached global->LDS (read-only data: weights, x)
__device__ __forceinline__ void gll16_c(const void* g, void* l) {
    __builtin_amdgcn_global_load_lds(
        (const __attribute__((address_space(1))) unsigned int*)g,
        (__attribute__((address_space(3))) unsigned int*)l, 16, 0, 0);
}
// coherent global->LDS: aux=17 = sc0|sc1 (bypass L1+L2, read at MALL) for h
__device__ __forceinline__ void gll16_v(const void* g, void* l) {
    __builtin_amdgcn_global_load_lds(
        (const __attribute__((address_space(1))) unsigned int*)g,
        (__attribute__((address_space(3))) unsigned int*)l, 16, 0, 17);
}

__device__ __forceinline__ float sig_(float x) { return 1.0f / (1.0f + __expf(-x)); }
__device__ __forceinline__ float tanh_(float x) {
    float e = __expf(-2.0f * fabsf(x));
    float t = (1.0f - e) / (1.0f + e);
    return copysignf(t, x);
}

// device-scope coherent h store (write-through to MALL)
__device__ __forceinline__ void store_h_dev(__bf16* p, float hv) {
    __bf16 hb = (__bf16)hv;
    unsigned v = (unsigned)__builtin_bit_cast(unsigned short, hb);
    asm volatile("global_store_short %0, %1, off sc0 sc1" :: "v"(p), "v"(v) : "memory");
}

// counted vmcnt wait (compile-time imm after unroll) + scheduler pin
__device__ __forceinline__ void waitv_imm(int n) {
    if (n >= 24)      asm volatile("s_waitcnt vmcnt(24)" ::: "memory");
    else if (n == 16) asm volatile("s_waitcnt vmcnt(16)" ::: "memory");
    else if (n == 8)  asm volatile("s_waitcnt vmcnt(8)"  ::: "memory");
    else              asm volatile("s_waitcnt vmcnt(0)"  ::: "memory");
    __builtin_amdgcn_sched_barrier(0);
}

// raw block barrier: does NOT drain vmcnt (loads stay in flight across it).
// lgkmcnt(0) forces this wave's ds_reads complete (buffer reuse safety).
__device__ __forceinline__ void block_bar() {
    __builtin_amdgcn_sched_barrier(0);
    asm volatile("s_waitcnt lgkmcnt(0)\n\ts_barrier" ::: "memory");
    __builtin_amdgcn_sched_barrier(0);
}

// coherent flag read: plain MALL load, no line ownership (unlike RMW poll)
__device__ __forceinline__ unsigned gen_load(const unsigned* p) {
    unsigned v;
    asm volatile("global_load_dword %0, %1, off sc0 sc1\n\ts_waitcnt vmcnt(0)"
                 : "=v"(v) : "v"(p) : "memory");
    return v;
}

// -------- group barrier (32 blocks sharing one rt) --------
struct __align__(64) Bar { unsigned cnt; unsigned gen; unsigned pad[14]; };

__device__ __forceinline__ void arrive_poll(Bar* b, unsigned n, unsigned e) {
    unsigned prev = __hip_atomic_fetch_add(&b->cnt, 1u, __ATOMIC_RELAXED, __HIP_MEMORY_SCOPE_AGENT);
    if (prev == e * n - 1u) {
        __hip_atomic_fetch_add(&b->gen, 1u, __ATOMIC_RELAXED, __HIP_MEMORY_SCOPE_AGENT);
    } else {
        unsigned spins = 0;
        while (gen_load(&b->gen) < e) {
            __builtin_amdgcn_s_sleep(1);
            if (++spins > (1u << 17)) break;   // failsafe: fail loud, never hang
        }
    }
}

struct Params {
    const __bf16* xbf;
    const __bf16* wT1;
    const __bf16* wT2;
    const float *b1u, *b1f, *b1o, *b1c;
    const float *b2u, *b2f, *b2o, *b2c;
    __bf16* hA;
    __bf16* hB;
    float*  out;
    Bar*    bars;
};

// ---- one staging group = B-iter (4 gll16) + A-iter (4 gll16) per thread ----
// LDS: A buffers [0,4096) 16B-units (4 x 1024), B buffers [4096,8192).
template<int XIT>
__device__ __forceinline__ void issue_group(bf16x8* smem,
    const __bf16* __restrict__ ax, const __bf16* __restrict__ ah,
    const __bf16* __restrict__ wrow, int it, int row, int kgb)
{
    const int bb = (it & 3) * 1024;
    const int k0 = it * 64;
    #pragma unroll
    for (int i = 0; i < 4; ++i) {
        const int kg = kgb + 2 * i;
        gll16_c(wrow + k0 + kg * 8, &smem[4096 + bb + kg * 128 + row]);
    }
    if (XIT > 0 && it < XIT) {      // A from x (cached)
        #pragma unroll
        for (int i = 0; i < 4; ++i) {
            const int kg = kgb + 2 * i;
            gll16_c(ax + (size_t)row * ND + k0 + kg * 8, &smem[bb + kg * 128 + row]);
        }
    } else {                         // A from h (coherent MALL read)
        #pragma unroll
        for (int i = 0; i < 4; ++i) {
            const int kg = kgb + 2 * i;
            gll16_v(ah + (size_t)row * NS + (k0 - XIT * 64) + kg * 8, &smem[bb + kg * 128 + row]);
        }
    }
}

// ---- pipelined GEMM: depth-4 buffers, counted vmcnt, raw barriers ----
template<int NIT, int XIT, bool PRE>
__device__ __forceinline__ void gemm_pipe(bf16x8* smem,
    const __bf16* __restrict__ ax, const __bf16* __restrict__ ah,
    const __bf16* __restrict__ wrow,
    f32x4 (&acc)[4][4], int lane, int wr, int ws, int row, int kgb)
{
    if (!PRE) {
        issue_group<XIT>(smem, ax, ah, wrow, 0, row, kgb);
        issue_group<XIT>(smem, ax, ah, wrow, 1, row, kgb);
        issue_group<XIT>(smem, ax, ah, wrow, 2, row, kgb);
    }
    #pragma unroll
    for (int it = 0; it < NIT; ++it) {
        if (it + 3 < NIT) issue_group<XIT>(smem, ax, ah, wrow, it + 3, row, kgb);
        const int rem = NIT - 1 - it;
        waitv_imm(rem >= 3 ? 24 : rem * 8);   // group `it` landed; rest in flight
        block_bar();                          // all waves' group `it` landed
        const int bb = (it & 3) * 1024;
        #pragma unroll
        for (int sub = 0; sub < 2; ++sub) {
            const int kq = sub * 4 + (lane >> 4);
            bf16x8 a[4], b[4];
            #pragma unroll
            for (int mI = 0; mI < 4; ++mI)
                a[mI] = smem[bb + kq * 128 + wr + mI * 16 + (lane & 15)];
            #pragma unroll
            for (int g = 0; g < 4; ++g)
                b[g] = smem[4096 + bb + kq * 128 + g * 32 + ws * 16 + (lane & 15)];
            #pragma unroll
            for (int mI = 0; mI < 4; ++mI)
                #pragma unroll
                for (int g = 0; g < 4; ++g)
                    acc[mI][g] = __builtin_amdgcn_mfma_f32_16x16x32_bf16(a[mI], b[g], acc[mI][g], 0, 0, 0);
        }
        block_bar();                          // all waves done reading buf it&3
    }
}

// ---- in-lane LSTM epilogue (gate-major: gates live in acc[mI][0..3]) ----
template<bool LAST>
__device__ __forceinline__ void epilogue(const f32x4 (&acc)[4][4], float (&m_reg)[16],
    float bu, float bf_, float bo, float bc,
    __bf16* __restrict__ hout, float* __restrict__ out,
    int rbase, int scol, int dof, int colL)
{
    #pragma unroll
    for (int mI = 0; mI < 4; ++mI) {
        #pragma unroll
        for (int r = 0; r < 4; ++r) {
            const int row = rbase + mI * 16 + r;   // batch row in [0, 512)
            const float gu = sig_(acc[mI][0][r] + bu);
            const float gf = sig_(acc[mI][1][r] + bf_);
            const float go = sig_(acc[mI][2][r] + bo);
            const float gc = tanh_(acc[mI][3][r] + bc);
            float& m = m_reg[mI * 4 + r];
            m = gf * m + gu * gc;
            const float hv = tanh_(go * m);
            if (LAST) {
                const size_t oi = ((size_t)dof * NB + row) * ND + colL;
                out[oi] = hv;
                out[(size_t)NDOF * NB * ND + oi] = m;
            } else {
                store_h_dev(&hout[(size_t)row * NS + scol], hv);
            }
        }
    }
}

// 128 blocks x 256 threads, 128 KB LDS: 1 block/CU, all co-resident (2x CU
// margin) -> group spin barriers are deadlock-free.
__global__ __launch_bounds__(256, 1)
void lstm_persistent(Params p)
{
    __shared__ bf16x8 smem[8192];   // 128 KB: A 4-deep [0,4096), B 4-deep [4096,8192)

    const int tid  = threadIdx.x;
    const int lane = tid & 63;
    const int wv   = tid >> 6;
    const int wr   = (wv >> 1) * 64;     // wave row-half
    const int ws   = wv & 1;             // wave col-strip (16 cols per gate)
    const int nt   = blockIdx.x & 31;    // nt%8 spreads weight panels across XCDs
    const int rt   = blockIdx.x >> 5;    // [0, NRT)
    const int r0   = rt * 128;
    const int dof  = nt >> 3;
    const int c0   = (nt & 7) * 32;

    const int row  = tid & 127;          // staging row
    const int kgb  = (tid >> 7) & 1;     // staging k-group base

    const int colL = c0 + ws * 16 + (lane & 15);   // col within dof [0,256)
    const int scol = dof * ND + colL;              // col in state row [0,1024)
    const int rbase = r0 + wr + (lane >> 4) * 4;

    // per-thread weight row (n' = dof*1024 + g*256 + col, k-contiguous)
    const int rowT = tid & 127;
    const int npT  = dof * 1024 + (rowT >> 5) * 256 + c0 + (rowT & 31);
    const __bf16* wrow1 = p.wT1 + (size_t)npT * 512;
    const __bf16* wrow2 = p.wT2 + (size_t)npT * 1024;

    const __bf16* ahA = p.hA + (size_t)r0 * NS + dof * ND;  // phase-1 h base
    const __bf16* ahB = p.hB + (size_t)r0 * NS;             // phase-2 h base

    const float b1u = p.b1u[scol], b1f = p.b1f[scol], b1o = p.b1o[scol], b1c = p.b1c[scol];
    const float b2u = p.b2u[scol], b2f = p.b2f[scol], b2o = p.b2o[scol], b2c = p.b2c[scol];

    float m_reg[16];
    #pragma unroll
    for (int i = 0; i < 16; ++i) m_reg[i] = 0.f;

    Bar* barA = &p.bars[rt * 2 + 0];
    Bar* barB = &p.bars[rt * 2 + 1];

    // pre-issue step-0 phase-1 prologue (groups 0-2: x + wT1, no h dependency)
    {
        const __bf16* ax0 = p.xbf + ((size_t)(dof * NT) * NB + r0) * ND;
        issue_group<4>(smem, ax0, ahA, wrow1, 0, row, kgb);
        issue_group<4>(smem, ax0, ahA, wrow1, 1, row, kgb);
        issue_group<4>(smem, ax0, ahA, wrow1, 2, row, kgb);
    }

    for (int t = 0; t < NT; ++t) {
        // ---------- phase 1: per-dof cell, K=512 = [x_t | h_own] ----------
        f32x4 acc[4][4];
        #pragma unroll
        for (int mI = 0; mI < 4; ++mI)
            #pragma unroll
            for (int g = 0; g < 4; ++g) acc[mI][g] = (f32x4){0.f, 0.f, 0.f, 0.f};

        const __bf16* ax = p.xbf + ((size_t)(dof * NT + t) * NB + r0) * ND;
        gemm_pipe<8, 4, true>(smem, ax, ahA, wrow1, acc, lane, wr, ws, row, kgb);
        epilogue<false>(acc, m_reg, b1u, b1f, b1o, b1c, p.hB, nullptr, rbase, scol, dof, colL);

        // barA: h-stores drained, then arrive+poll (no full-L2 maintenance)
        asm volatile("s_waitcnt vmcnt(0)" ::: "memory");
        block_bar();
        if (tid == 0) arrive_poll(barA, 32, (unsigned)(t + 1));
        block_bar();

        // ---------- phase 2: grid coupling, K=1024 = full h row ----------
        #pragma unroll
        for (int mI = 0; mI < 4; ++mI)
            #pragma unroll
            for (int g = 0; g < 4; ++g) acc[mI][g] = (f32x4){0.f, 0.f, 0.f, 0.f};

        gemm_pipe<16, 0, false>(smem, nullptr, ahB, wrow2, acc, lane, wr, ws, row, kgb);

        if (t + 1 < NT) {
            epilogue<false>(acc, m_reg, b2u, b2f, b2o, b2c, p.hA, nullptr, rbase, scol, dof, colL);
            // pre-issue next step's phase-1 prologue (x + wT1, barrier-independent);
            // its latency hides under the barB spin.
            const __bf16* axn = p.xbf + ((size_t)(dof * NT + t + 1) * NB + r0) * ND;
            issue_group<4>(smem, axn, ahA, wrow1, 0, row, kgb);
            issue_group<4>(smem, axn, ahA, wrow1, 1, row, kgb);
            issue_group<4>(smem, axn, ahA, wrow1, 2, row, kgb);
            // barB: wait only for the 16 h-stores (oldest); 24 prologue loads stay in flight
            asm volatile("s_waitcnt vmcnt(24)" ::: "memory");
            block_bar();
            if (tid == 0) arrive_poll(barB, 32, (unsigned)(t + 1));
            block_bar();
        } else {
            epilogue<true>(acc, m_reg, b2u, b2f, b2o, b2c, p.hA, p.out, rbase, scol, dof, colL);
        }
    }
}

// ---- one-time prep: x[d][b][t][:] fp32 -> xbf[d][t][b][:] bf16 ----
__global__ __launch_bounds__(256)
void convert_x(const float* __restrict__ x, __bf16* __restrict__ xbf)
{
    const int id  = blockIdx.x * 256 + threadIdx.x;   // 4,194,304 total
    const int d0  = (id & 31) * 8;
    const int t   = (id >> 5) & 63;
    const int b   = (id >> 11) & 511;
    const int dof = id >> 20;
    const float* s = x + (((size_t)dof * NB + b) * NT + t) * ND + d0;
    const float4 v0 = *(const float4*)s;
    const float4 v1 = *(const float4*)(s + 4);
    bf16x8 o;
    o[0] = (__bf16)v0.x; o[1] = (__bf16)v0.y; o[2] = (__bf16)v0.z; o[3] = (__bf16)v0.w;
    o[4] = (__bf16)v1.x; o[5] = (__bf16)v1.y; o[6] = (__bf16)v1.z; o[7] = (__bf16)v1.w;
    *(bf16x8*)(xbf + (((size_t)dof * NT + t) * NB + b) * ND + d0) = o;
}

// ---- one-time prep: weights -> bf16 wT[n'][k], n' = dof*1024 + g*256 + col ----
__global__ __launch_bounds__(256)
void transpose_weights(const float* __restrict__ wu, const float* __restrict__ wf,
                       const float* __restrict__ wo, const float* __restrict__ wcp,
                       const float* __restrict__ gwu, const float* __restrict__ gwf,
                       const float* __restrict__ gwo, const float* __restrict__ gwc,
                       __bf16* __restrict__ wT1, __bf16* __restrict__ wT2)
{
    int id = blockIdx.x * 256 + threadIdx.x;
    const int C1 = 4096 * 64;
    int K, np, kc;
    const float *s0, *s1, *s2, *s3;
    __bf16* dst;
    if (id < C1) { K = 512;  np = id & 4095; kc = id >> 12; dst = wT1; s0 = wu;  s1 = wf;  s2 = wo;  s3 = wcp; }
    else { id -= C1; K = 1024; np = id & 4095; kc = id >> 12; dst = wT2; s0 = gwu; s1 = gwf; s2 = gwo; s3 = gwc; }
    const int dof = np >> 10, q = np & 1023, g = q >> 8, col = q & 255;
    const float* w = ((g == 0) ? s0 : (g == 1) ? s1 : (g == 2) ? s2 : s3)
                     + ((size_t)dof * K + kc * 8) * ND + col;
    bf16x8 o;
    #pragma unroll
    for (int j = 0; j < 8; ++j) o[j] = (__bf16)w[j * ND];
    *(bf16x8*)(dst + (size_t)np * K + kc * 8) = o;
}

extern "C" void kernel_launch(void* const* d_in, const int* in_sizes, int n_in,
                              void* d_out, int out_size, void* d_ws, size_t ws_size,
                              hipStream_t stream)
{
    const float* x   = (const float*)d_in[0];
    const float* wu  = (const float*)d_in[1];
    const float* wf  = (const float*)d_in[2];
    const float* wo  = (const float*)d_in[3];
    const float* wc  = (const float*)d_in[4];

    char* ws = (char*)d_ws;
    __bf16* wT1 = (__bf16*)ws;                        //  4 MB  [4096][512]
    __bf16* wT2 = (__bf16*)(ws + (4u  << 20));        //  8 MB  [4096][1024]
    __bf16* xbf = (__bf16*)(ws + (12u << 20));        // 64 MB  [4][64][512][256]
    __bf16* hA  = (__bf16*)(ws + (76u << 20));        //  1 MB
    __bf16* hB  = (__bf16*)(ws + (77u << 20));        //  1 MB
    Bar*    bars = (Bar*)  (ws + (78u << 20));        //  1 KB (16 x 64B)

    convert_x<<<16384, 256, 0, stream>>>(x, xbf);
    transpose_weights<<<3072, 256, 0, stream>>>(
        wu, wf, wo, wc,
        (const float*)d_in[9], (const float*)d_in[10],
        (const float*)d_in[11], (const float*)d_in[12], wT1, wT2);
    // zero hA + hB + barrier state each call (deterministic across replays)
    hipMemsetAsync(ws + (76u << 20), 0, (2u << 20) + 4096, stream);

    Params p;
    p.xbf = xbf; p.wT1 = wT1; p.wT2 = wT2;
    p.b1u = (const float*)d_in[5];  p.b1f = (const float*)d_in[6];
    p.b1o = (const float*)d_in[7];  p.b1c = (const float*)d_in[8];
    p.b2u = (const float*)d_in[13]; p.b2f = (const float*)d_in[14];
    p.b2o = (const float*)d_in[15]; p.b2c = (const float*)d_in[16];
    p.hA = hA; p.hB = hB; p.out = (float*)d_out; p.bars = bars;

    lstm_persistent<<<dim3(GRID), dim3(256), 0, stream>>>(p);
}

// Round 8
// 2667.275 us; speedup vs baseline: 1.4839x; 1.4839x over previous
//
#include <hip/hip_runtime.h>
#include <math.h>

#define NDOF 4
#define NB   512
#define NT   64
#define ND   256
#define NS   1024           // NDOF*ND

// 128 blocks = 4 rt (128-row batch tiles) x 32 nt (128 n'-cols).
#define NRT  4
#define GRID (NRT * 32)

typedef __attribute__((ext_vector_type(8))) __bf16 bf16x8;
typedef __attribute__((ext_vector_type(4))) float  f32x4;

// cached global->LDS (weights, x, and ring-h: ring slots are write-once, so
// cached reads are coherent -- no address is re-read after a remote write)
__device__ __forceinline__ void gll16(const void* g, void* l) {
    __builtin_amdgcn_global_load_lds(
        (const __attribute__((address_space(1))) unsigned int*)g,
        (__attribute__((address_space(3))) unsigned int*)l, 16, 0, 0);
}

__device__ __forceinline__ float sig_(float x) { return 1.0f / (1.0f + __expf(-x)); }
__device__ __forceinline__ float tanh_(float x) {
    float e = __expf(-2.0f * fabsf(x));
    float t = (1.0f - e) / (1.0f + e);
    return copysignf(t, x);
}

// h store: sc0 sc1 write-through to MALL (globally visible once vmcnt-retired)
__device__ __forceinline__ void store_h_dev(__bf16* p, float hv) {
    __bf16 hb = (__bf16)hv;
    unsigned v = (unsigned)__builtin_bit_cast(unsigned short, hb);
    asm volatile("global_store_short %0, %1, off sc0 sc1" :: "v"(p), "v"(v) : "memory");
}

__device__ __forceinline__ void waitv_imm(int n) {
    if (n >= 24)      asm volatile("s_waitcnt vmcnt(24)" ::: "memory");
    else if (n == 16) asm volatile("s_waitcnt vmcnt(16)" ::: "memory");
    else if (n == 12) asm volatile("s_waitcnt vmcnt(12)" ::: "memory");
    else if (n == 8)  asm volatile("s_waitcnt vmcnt(8)"  ::: "memory");
    else              asm volatile("s_waitcnt vmcnt(0)"  ::: "memory");
    __builtin_amdgcn_sched_barrier(0);
}

// raw block barrier: does NOT drain vmcnt (loads stay in flight across it).
__device__ __forceinline__ void block_bar() {
    __builtin_amdgcn_sched_barrier(0);
    asm volatile("s_waitcnt lgkmcnt(0)\n\ts_barrier" ::: "memory");
    __builtin_amdgcn_sched_barrier(0);
}

// coherent flag read (wave0 has nothing in flight at poll points)
__device__ __forceinline__ unsigned gen_load(const unsigned* p) {
    unsigned v;
    asm volatile("global_load_dword %0, %1, off sc0 sc1\n\ts_waitcnt vmcnt(0)"
                 : "=v"(v) : "v"(p) : "memory");
    return v;
}

// -------- group barrier (32 blocks sharing one rt) --------
struct __align__(64) Bar { unsigned cnt; unsigned gen; unsigned pad[14]; };

__device__ __forceinline__ void arrive_poll(Bar* b, unsigned n, unsigned e) {
    unsigned prev = __hip_atomic_fetch_add(&b->cnt, 1u, __ATOMIC_RELAXED, __HIP_MEMORY_SCOPE_AGENT);
    if (prev == e * n - 1u) {
        __hip_atomic_fetch_add(&b->gen, 1u, __ATOMIC_RELAXED, __HIP_MEMORY_SCOPE_AGENT);
    } else {
        unsigned spins = 0;
        while (gen_load(&b->gen) < e) {
            __builtin_amdgcn_s_sleep(1);
            if (++spins > (1u << 17)) break;   // failsafe: fail loud, never hang
        }
    }
}

struct Params {
    const __bf16* xbf;
    const __bf16* wT1;
    const __bf16* wT2;
    const float *b1u, *b1f, *b1o, *b1c;
    const float *b2u, *b2f, *b2o, *b2c;
    const __bf16* hInit;   // 1 MB zeros [512][1024]
    __bf16* ring;          // [NT*2] slots of [512][1024] bf16 (1 MB each)
    float*  out;
    Bar*    bars;
};

// ---- pair staging: B = weights (cached), A = x or ring-h (cached) ----
// LDS 16B-units: A 4-deep [0,4096), B 4-deep [4096,8192); pair buffer = pair&3.
__device__ __forceinline__ void issueB(bf16x8* smem, const __bf16* wrow,
                                       int pair, int row, int kgb) {
    const int bb = 4096 + (pair & 3) * 1024;
    const int k0 = pair * 64;
    #pragma unroll
    for (int i = 0; i < 4; ++i) {
        const int kg = kgb + 2 * i;
        gll16(wrow + k0 + kg * 8, &smem[bb + kg * 128 + row]);
    }
}
template<int XIT>
__device__ __forceinline__ void issueA(bf16x8* smem, const __bf16* ax,
                                       const __bf16* ah, int pair, int row, int kgb) {
    const int bb = (pair & 3) * 1024;
    const __bf16* base;
    if (XIT > 0 && pair < XIT) base = ax + (size_t)row * ND + pair * 64;
    else                       base = ah + (size_t)row * NS + (pair - XIT) * 64;
    #pragma unroll
    for (int i = 0; i < 4; ++i) {
        const int kg = kgb + 2 * i;
        gll16(base + kg * 8, &smem[bb + kg * 128 + row]);
    }
}

// ---- GEMM core. Pairs 0-2 (B then A order) must be pre-issued by caller.
// vmcnt table (hand-verified for prologue order B0B1B2 A0A1A2, +8/iter):
// it0->8, it1->12, it==NIT-2->8, it==NIT-1->0, else 16.
template<int NIT, int XIT>
__device__ __forceinline__ void gemm_core(bf16x8* smem,
    const __bf16* ax, const __bf16* ah, const __bf16* wrow,
    f32x4 (&acc)[4][4], int lane, int wr, int ws, int row, int kgb)
{
    #pragma unroll
    for (int it = 0; it < NIT; ++it) {
        waitv_imm(it == 0 ? 8 : it == 1 ? 12 :
                  it >= NIT - 1 ? 0 : it == NIT - 2 ? 8 : 16);
        block_bar();   // all waves' pair(it) landed; buffers (it+3)&3 free
        if (it + 3 < NIT) {
            issueB(smem, wrow, it + 3, row, kgb);
            issueA<XIT>(smem, ax, ah, it + 3, row, kgb);
        }
        const int bb = (it & 3) * 1024;
        #pragma unroll
        for (int sub = 0; sub < 2; ++sub) {
            const int kq = sub * 4 + (lane >> 4);
            bf16x8 a[4], b[4];
            #pragma unroll
            for (int mI = 0; mI < 4; ++mI)
                a[mI] = smem[bb + kq * 128 + wr + mI * 16 + (lane & 15)];
            #pragma unroll
            for (int g = 0; g < 4; ++g)
                b[g] = smem[4096 + bb + kq * 128 + g * 32 + ws * 16 + (lane & 15)];
            #pragma unroll
            for (int mI = 0; mI < 4; ++mI)
                #pragma unroll
                for (int g = 0; g < 4; ++g)
                    acc[mI][g] = __builtin_amdgcn_mfma_f32_16x16x32_bf16(a[mI], b[g], acc[mI][g], 0, 0, 0);
        }
    }
}

// ---- in-lane LSTM epilogue (gate-major: gates live in acc[mI][0..3]) ----
template<bool LAST>
__device__ __forceinline__ void epilogue(const f32x4 (&acc)[4][4], float (&m_reg)[16],
    float bu, float bf_, float bo, float bc,
    __bf16* __restrict__ hout, float* __restrict__ out,
    int rbase, int scol, int dof, int colL)
{
    #pragma unroll
    for (int mI = 0; mI < 4; ++mI) {
        #pragma unroll
        for (int r = 0; r < 4; ++r) {
            const int row = rbase + mI * 16 + r;
            const float gu = sig_(acc[mI][0][r] + bu);
            const float gf = sig_(acc[mI][1][r] + bf_);
            const float go = sig_(acc[mI][2][r] + bo);
            const float gc = tanh_(acc[mI][3][r] + bc);
            float& m = m_reg[mI * 4 + r];
            m = gf * m + gu * gc;
            const float hv = tanh_(go * m);
            if (LAST) {
                const size_t oi = ((size_t)dof * NB + row) * ND + colL;
                out[oi] = hv;
                out[(size_t)NDOF * NB * ND + oi] = m;
            } else {
                store_h_dev(&hout[(size_t)row * NS + scol], hv);
            }
        }
    }
}

__global__ __launch_bounds__(256, 1)
void lstm_persistent(Params p)
{
    __shared__ bf16x8 smem[8192];   // 128 KB: A 4-deep, B 4-deep

    const int tid  = threadIdx.x;
    const int lane = tid & 63;
    const int wv   = tid >> 6;
    const int wr   = (wv >> 1) * 64;
    const int ws   = wv & 1;
    const int nt   = blockIdx.x & 31;    // nt%8 = XCD -> weight panels L2-resident
    const int rt   = blockIdx.x >> 5;
    const int r0   = rt * 128;
    const int dof  = nt >> 3;
    const int c0   = (nt & 7) * 32;

    const int row  = tid & 127;
    const int kgb  = (tid >> 7) & 1;

    const int colL = c0 + ws * 16 + (lane & 15);
    const int scol = dof * ND + colL;
    const int rbase = r0 + wr + (lane >> 4) * 4;

    const int rowT = tid & 127;
    const int npT  = dof * 1024 + (rowT >> 5) * 256 + c0 + (rowT & 31);
    const __bf16* wrow1 = p.wT1 + (size_t)npT * 512;
    const __bf16* wrow2 = p.wT2 + (size_t)npT * 1024;

    const float b1u = p.b1u[scol], b1f = p.b1f[scol], b1o = p.b1o[scol], b1c = p.b1c[scol];
    const float b2u = p.b2u[scol], b2f = p.b2f[scol], b2o = p.b2o[scol], b2c = p.b2c[scol];

    float m_reg[16];
    #pragma unroll
    for (int i = 0; i < 16; ++i) m_reg[i] = 0.f;

    Bar* barA = &p.bars[rt * 2 + 0];
    Bar* barB = &p.bars[rt * 2 + 1];

    auto slot = [&](int i) -> __bf16* { return p.ring + ((size_t)i << 19); };

    // kernel-start prologue for t=0 phase-1 (B then A order -- fixed!)
    {
        const __bf16* ax0 = p.xbf + ((size_t)(dof * NT) * NB + r0) * ND;
        const __bf16* ah0 = p.hInit + (size_t)r0 * NS + dof * ND;
        issueB(smem, wrow1, 0, row, kgb); issueB(smem, wrow1, 1, row, kgb); issueB(smem, wrow1, 2, row, kgb);
        issueA<4>(smem, ax0, ah0, 0, row, kgb); issueA<4>(smem, ax0, ah0, 1, row, kgb); issueA<4>(smem, ax0, ah0, 2, row, kgb);
    }

    for (int t = 0; t < NT; ++t) {
        const __bf16* ax  = p.xbf + ((size_t)(dof * NT + t) * NB + r0) * ND;
        const __bf16* ah1 = (t == 0 ? p.hInit : slot(2 * t - 1)) + (size_t)r0 * NS + dof * ND;
        __bf16* h1out = slot(2 * t);
        const __bf16* ah2 = slot(2 * t) + (size_t)r0 * NS;
        __bf16* h2out = slot(2 * t + 1);

        // ---------- phase 1: per-dof cell, K=512 = [x_t | h_own] ----------
        f32x4 acc[4][4];
        #pragma unroll
        for (int mI = 0; mI < 4; ++mI)
            #pragma unroll
            for (int g = 0; g < 4; ++g) acc[mI][g] = (f32x4){0.f, 0.f, 0.f, 0.f};

        gemm_core<8, 4>(smem, ax, ah1, wrow1, acc, lane, wr, ws, row, kgb);
        epilogue<false>(acc, m_reg, b1u, b1f, b1o, b1c, h1out, nullptr, rbase, scol, dof, colL);

        // barA: waves 1-3 pre-issue phase-2 B prologue (barrier-independent),
        // then each wave drains its own h-stores; wave0 issues B after poll.
        if (wv != 0) {
            issueB(smem, wrow2, 0, row, kgb); issueB(smem, wrow2, 1, row, kgb); issueB(smem, wrow2, 2, row, kgb);
            waitv_imm(12);
        } else {
            waitv_imm(0);
        }
        block_bar();
        if (tid == 0) arrive_poll(barA, 32, (unsigned)(t + 1));
        block_bar();
        if (wv == 0) {
            issueB(smem, wrow2, 0, row, kgb); issueB(smem, wrow2, 1, row, kgb); issueB(smem, wrow2, 2, row, kgb);
        }
        issueA<0>(smem, nullptr, ah2, 0, row, kgb);
        issueA<0>(smem, nullptr, ah2, 1, row, kgb);
        issueA<0>(smem, nullptr, ah2, 2, row, kgb);

        // ---------- phase 2: grid coupling, K=1024 = full h row ----------
        #pragma unroll
        for (int mI = 0; mI < 4; ++mI)
            #pragma unroll
            for (int g = 0; g < 4; ++g) acc[mI][g] = (f32x4){0.f, 0.f, 0.f, 0.f};

        gemm_core<16, 0>(smem, nullptr, ah2, wrow2, acc, lane, wr, ws, row, kgb);

        if (t + 1 < NT) {
            epilogue<false>(acc, m_reg, b2u, b2f, b2o, b2c, h2out, nullptr, rbase, scol, dof, colL);
            const __bf16* axn  = p.xbf + ((size_t)(dof * NT + t + 1) * NB + r0) * ND;
            const __bf16* ah1n = slot(2 * t + 1) + (size_t)r0 * NS + dof * ND;  // not read in pairs 0-2
            if (wv != 0) {   // full next-phase-1 prologue is barrier-independent (pairs 0-2 are x)
                issueB(smem, wrow1, 0, row, kgb); issueB(smem, wrow1, 1, row, kgb); issueB(smem, wrow1, 2, row, kgb);
                issueA<4>(smem, axn, ah1n, 0, row, kgb); issueA<4>(smem, axn, ah1n, 1, row, kgb); issueA<4>(smem, axn, ah1n, 2, row, kgb);
                waitv_imm(24);
            } else {
                waitv_imm(0);
            }
            block_bar();
            if (tid == 0) arrive_poll(barB, 32, (unsigned)(t + 1));
            block_bar();
            if (wv == 0) {
                issueB(smem, wrow1, 0, row, kgb); issueB(smem, wrow1, 1, row, kgb); issueB(smem, wrow1, 2, row, kgb);
                issueA<4>(smem, axn, ah1n, 0, row, kgb); issueA<4>(smem, axn, ah1n, 1, row, kgb); issueA<4>(smem, axn, ah1n, 2, row, kgb);
            }
        } else {
            epilogue<true>(acc, m_reg, b2u, b2f, b2o, b2c, nullptr, p.out, rbase, scol, dof, colL);
        }
    }
}

// ---- one-time prep: x[d][b][t][:] fp32 -> xbf[d][t][b][:] bf16 ----
__global__ __launch_bounds__(256)
void convert_x(const float* __restrict__ x, __bf16* __restrict__ xbf)
{
    const int id  = blockIdx.x * 256 + threadIdx.x;
    const int d0  = (id & 31) * 8;
    const int t   = (id >> 5) & 63;
    const int b   = (id >> 11) & 511;
    const int dof = id >> 20;
    const float* s = x + (((size_t)dof * NB + b) * NT + t) * ND + d0;
    const float4 v0 = *(const float4*)s;
    const float4 v1 = *(const float4*)(s + 4);
    bf16x8 o;
    o[0] = (__bf16)v0.x; o[1] = (__bf16)v0.y; o[2] = (__bf16)v0.z; o[3] = (__bf16)v0.w;
    o[4] = (__bf16)v1.x; o[5] = (__bf16)v1.y; o[6] = (__bf16)v1.z; o[7] = (__bf16)v1.w;
    *(bf16x8*)(xbf + (((size_t)dof * NT + t) * NB + b) * ND + d0) = o;
}

// ---- one-time prep: weights -> bf16 wT[n'][k], n' = dof*1024 + g*256 + col ----
__global__ __launch_bounds__(256)
void transpose_weights(const float* __restrict__ wu, const float* __restrict__ wf,
                       const float* __restrict__ wo, const float* __restrict__ wcp,
                       const float* __restrict__ gwu, const float* __restrict__ gwf,
                       const float* __restrict__ gwo, const float* __restrict__ gwc,
                       __bf16* __restrict__ wT1, __bf16* __restrict__ wT2)
{
    int id = blockIdx.x * 256 + threadIdx.x;
    const int C1 = 4096 * 64;
    int K, np, kc;
    const float *s0, *s1, *s2, *s3;
    __bf16* dst;
    if (id < C1) { K = 512;  np = id & 4095; kc = id >> 12; dst = wT1; s0 = wu;  s1 = wf;  s2 = wo;  s3 = wcp; }
    else { id -= C1; K = 1024; np = id & 4095; kc = id >> 12; dst = wT2; s0 = gwu; s1 = gwf; s2 = gwo; s3 = gwc; }
    const int dof = np >> 10, q = np & 1023, g = q >> 8, col = q & 255;
    const float* w = ((g == 0) ? s0 : (g == 1) ? s1 : (g == 2) ? s2 : s3)
                     + ((size_t)dof * K + kc * 8) * ND + col;
    bf16x8 o;
    #pragma unroll
    for (int j = 0; j < 8; ++j) o[j] = (__bf16)w[j * ND];
    *(bf16x8*)(dst + (size_t)np * K + kc * 8) = o;
}

extern "C" void kernel_launch(void* const* d_in, const int* in_sizes, int n_in,
                              void* d_out, int out_size, void* d_ws, size_t ws_size,
                              hipStream_t stream)
{
    const float* x   = (const float*)d_in[0];
    const float* wu  = (const float*)d_in[1];
    const float* wf  = (const float*)d_in[2];
    const float* wo  = (const float*)d_in[3];
    const float* wc  = (const float*)d_in[4];

    char* ws = (char*)d_ws;
    __bf16* wT1  = (__bf16*)ws;                        //   4 MB  [4096][512]
    __bf16* wT2  = (__bf16*)(ws + (4u  << 20));        //   8 MB  [4096][1024]
    __bf16* xbf  = (__bf16*)(ws + (12u << 20));        //  64 MB  [4][64][512][256]
    __bf16* hIn  = (__bf16*)(ws + (76u << 20));        //   1 MB  zeros
    Bar*    bars = (Bar*)  (ws + (78u << 20));         //   4 KB
    __bf16* ring = (__bf16*)(ws + (80u << 20));        // 128 MB  [NT*2][512][1024]

    convert_x<<<16384, 256, 0, stream>>>(x, xbf);
    transpose_weights<<<3072, 256, 0, stream>>>(
        wu, wf, wo, wc,
        (const float*)d_in[9], (const float*)d_in[10],
        (const float*)d_in[11], (const float*)d_in[12], wT1, wT2);
    // zero hInit + bars each call (covers 76..78 MB + 4 KB; deterministic)
    hipMemsetAsync(ws + (76u << 20), 0, (2u << 20) + 4096, stream);

    Params p;
    p.xbf = xbf; p.wT1 = wT1; p.wT2 = wT2;
    p.b1u = (const float*)d_in[5];  p.b1f = (const float*)d_in[6];
    p.b1o = (const float*)d_in[7];  p.b1c = (const float*)d_in[8];
    p.b2u = (const float*)d_in[13]; p.b2f = (const float*)d_in[14];
    p.b2o = (const float*)d_in[15]; p.b2c = (const float*)d_in[16];
    p.hInit = hIn; p.ring = ring; p.out = (float*)d_out; p.bars = bars;

    lstm_persistent<<<dim3(GRID), dim3(256), 0, stream>>>(p);
}

// Round 9
// 2613.728 us; speedup vs baseline: 1.5143x; 1.0205x over previous
//
#include <hip/hip_runtime.h>
#include <math.h>

#define NDOF 4
#define NB   512
#define NT   64
#define ND   256
#define NS   1024           // NDOF*ND

// 128 blocks; work→block mapping is XCD-aware (see lstm_persistent body).
#define NRT  4
#define GRID 128

typedef __attribute__((ext_vector_type(8))) __bf16 bf16x8;
typedef __attribute__((ext_vector_type(4))) float  f32x4;

// cached global->LDS (weights, x, and ring-h: ring slots are write-once, so
// cached reads are coherent -- no address is re-read after a remote write)
__device__ __forceinline__ void gll16(const void* g, void* l) {
    __builtin_amdgcn_global_load_lds(
        (const __attribute__((address_space(1))) unsigned int*)g,
        (__attribute__((address_space(3))) unsigned int*)l, 16, 0, 0);
}

__device__ __forceinline__ float sig_(float x) { return 1.0f / (1.0f + __expf(-x)); }
__device__ __forceinline__ float tanh_(float x) {
    float e = __expf(-2.0f * fabsf(x));
    float t = (1.0f - e) / (1.0f + e);
    return copysignf(t, x);
}

// h store: sc0 sc1 write-through to MALL (globally visible once vmcnt-retired)
__device__ __forceinline__ void store_h_dev(__bf16* p, float hv) {
    __bf16 hb = (__bf16)hv;
    unsigned v = (unsigned)__builtin_bit_cast(unsigned short, hb);
    asm volatile("global_store_short %0, %1, off sc0 sc1" :: "v"(p), "v"(v) : "memory");
}

__device__ __forceinline__ void waitv_imm(int n) {
    if (n >= 24)      asm volatile("s_waitcnt vmcnt(24)" ::: "memory");
    else if (n == 16) asm volatile("s_waitcnt vmcnt(16)" ::: "memory");
    else if (n == 12) asm volatile("s_waitcnt vmcnt(12)" ::: "memory");
    else if (n == 8)  asm volatile("s_waitcnt vmcnt(8)"  ::: "memory");
    else              asm volatile("s_waitcnt vmcnt(0)"  ::: "memory");
    __builtin_amdgcn_sched_barrier(0);
}

// raw block barrier: does NOT drain vmcnt (loads stay in flight across it).
__device__ __forceinline__ void block_bar() {
    __builtin_amdgcn_sched_barrier(0);
    asm volatile("s_waitcnt lgkmcnt(0)\n\ts_barrier" ::: "memory");
    __builtin_amdgcn_sched_barrier(0);
}

// coherent flag read (wave0 has nothing in flight at poll points)
__device__ __forceinline__ unsigned gen_load(const unsigned* p) {
    unsigned v;
    asm volatile("global_load_dword %0, %1, off sc0 sc1\n\ts_waitcnt vmcnt(0)"
                 : "=v"(v) : "v"(p) : "memory");
    return v;
}

// -------- group barrier (32 blocks sharing one rt) --------
struct __align__(64) Bar { unsigned cnt; unsigned gen; unsigned pad[14]; };

__device__ __forceinline__ void arrive_poll(Bar* b, unsigned n, unsigned e) {
    unsigned prev = __hip_atomic_fetch_add(&b->cnt, 1u, __ATOMIC_RELAXED, __HIP_MEMORY_SCOPE_AGENT);
    if (prev == e * n - 1u) {
        __hip_atomic_fetch_add(&b->gen, 1u, __ATOMIC_RELAXED, __HIP_MEMORY_SCOPE_AGENT);
    } else {
        unsigned spins = 0;
        while (gen_load(&b->gen) < e) {
            __builtin_amdgcn_s_sleep(1);
            if (++spins > (1u << 17)) break;   // failsafe: fail loud, never hang
        }
    }
}

struct Params {
    const __bf16* xbf;
    const __bf16* wT1;
    const __bf16* wT2;
    const float *b1u, *b1f, *b1o, *b1c;
    const float *b2u, *b2f, *b2o, *b2c;
    const __bf16* hInit;   // 1 MB zeros [512][1024]
    __bf16* ring;          // [NT*2] slots of [512][1024] bf16 (1 MB each)
    float*  out;
    Bar*    bars;
};

// ---- pair staging: B = weights (cached), A = x or ring-h (cached) ----
// LDS 16B-units: A 4-deep [0,4096), B 4-deep [4096,8192); pair buffer = pair&3.
__device__ __forceinline__ void issueB(bf16x8* smem, const __bf16* wrow,
                                       int pair, int row, int kgb) {
    const int bb = 4096 + (pair & 3) * 1024;
    const int k0 = pair * 64;
    #pragma unroll
    for (int i = 0; i < 4; ++i) {
        const int kg = kgb + 2 * i;
        gll16(wrow + k0 + kg * 8, &smem[bb + kg * 128 + row]);
    }
}
template<int XIT>
__device__ __forceinline__ void issueA(bf16x8* smem, const __bf16* ax,
                                       const __bf16* ah, int pair, int row, int kgb) {
    const int bb = (pair & 3) * 1024;
    const __bf16* base;
    if (XIT > 0 && pair < XIT) base = ax + (size_t)row * ND + pair * 64;
    else                       base = ah + (size_t)row * NS + (pair - XIT) * 64;
    #pragma unroll
    for (int i = 0; i < 4; ++i) {
        const int kg = kgb + 2 * i;
        gll16(base + kg * 8, &smem[bb + kg * 128 + row]);
    }
}

// ---- GEMM core. Pairs 0-2 (B then A order) must be pre-issued by caller.
// vmcnt table (hand-verified for prologue order B0B1B2 A0A1A2, +8/iter):
// it0->8, it1->12, it==NIT-2->8, it==NIT-1->0, else 16.
template<int NIT, int XIT>
__device__ __forceinline__ void gemm_core(bf16x8* smem,
    const __bf16* ax, const __bf16* ah, const __bf16* wrow,
    f32x4 (&acc)[4][4], int lane, int wr, int ws, int row, int kgb)
{
    #pragma unroll
    for (int it = 0; it < NIT; ++it) {
        waitv_imm(it == 0 ? 8 : it == 1 ? 12 :
                  it >= NIT - 1 ? 0 : it == NIT - 2 ? 8 : 16);
        block_bar();   // all waves' pair(it) landed; buffers (it+3)&3 free
        if (it + 3 < NIT) {
            issueB(smem, wrow, it + 3, row, kgb);
            issueA<XIT>(smem, ax, ah, it + 3, row, kgb);
        }
        const int bb = (it & 3) * 1024;
        #pragma unroll
        for (int sub = 0; sub < 2; ++sub) {
            const int kq = sub * 4 + (lane >> 4);
            bf16x8 a[4], b[4];
            #pragma unroll
            for (int mI = 0; mI < 4; ++mI)
                a[mI] = smem[bb + kq * 128 + wr + mI * 16 + (lane & 15)];
            #pragma unroll
            for (int g = 0; g < 4; ++g)
                b[g] = smem[4096 + bb + kq * 128 + g * 32 + ws * 16 + (lane & 15)];
            #pragma unroll
            for (int mI = 0; mI < 4; ++mI)
                #pragma unroll
                for (int g = 0; g < 4; ++g)
                    acc[mI][g] = __builtin_amdgcn_mfma_f32_16x16x32_bf16(a[mI], b[g], acc[mI][g], 0, 0, 0);
        }
    }
}

// ---- in-lane LSTM epilogue (gate-major: gates live in acc[mI][0..3]) ----
template<bool LAST>
__device__ __forceinline__ void epilogue(const f32x4 (&acc)[4][4], float (&m_reg)[16],
    float bu, float bf_, float bo, float bc,
    __bf16* __restrict__ hout, float* __restrict__ out,
    int rbase, int scol, int dof, int colL)
{
    #pragma unroll
    for (int mI = 0; mI < 4; ++mI) {
        #pragma unroll
        for (int r = 0; r < 4; ++r) {
            const int row = rbase + mI * 16 + r;
            const float gu = sig_(acc[mI][0][r] + bu);
            const float gf = sig_(acc[mI][1][r] + bf_);
            const float go = sig_(acc[mI][2][r] + bo);
            const float gc = tanh_(acc[mI][3][r] + bc);
            float& m = m_reg[mI * 4 + r];
            m = gf * m + gu * gc;
            const float hv = tanh_(go * m);
            if (LAST) {
                const size_t oi = ((size_t)dof * NB + row) * ND + colL;
                out[oi] = hv;
                out[(size_t)NDOF * NB * ND + oi] = m;
            } else {
                store_h_dev(&hout[(size_t)row * NS + scol], hv);
            }
        }
    }
}

__global__ __launch_bounds__(256, 1)
void lstm_persistent(Params p)
{
    __shared__ bf16x8 smem[8192];   // 128 KB: A 4-deep, B 4-deep

    const int tid  = threadIdx.x;
    const int lane = tid & 63;
    const int wv   = tid >> 6;
    const int wr   = (wv >> 1) * 64;
    const int ws   = wv & 1;

    // ---- XCD-aware work map (dispatch assigns bid -> XCD bid%8) ----
    // All 8 c-strips of a (dof, rt) group land on ONE XCD (x/h1 fetched once
    // per XCD); the 2 groups per XCD share dof (weight set 3 MB, L2-resident);
    // each rt spans 4 XCDs (phase-2 h tile replication 8x -> 4x).
    const int xcd   = blockIdx.x & 7;
    const int local = blockIdx.x >> 3;            // 0..15
    const int dof   = xcd & 3;
    const int rt    = ((xcd >> 2) << 1) | (local >> 3);   // 0..3
    const int c0    = (local & 7) * 32;
    const int r0    = rt * 128;

    const int row  = tid & 127;
    const int kgb  = (tid >> 7) & 1;

    const int colL = c0 + ws * 16 + (lane & 15);
    const int scol = dof * ND + colL;
    const int rbase = r0 + wr + (lane >> 4) * 4;

    const int rowT = tid & 127;
    const int npT  = dof * 1024 + (rowT >> 5) * 256 + c0 + (rowT & 31);
    const __bf16* wrow1 = p.wT1 + (size_t)npT * 512;
    const __bf16* wrow2 = p.wT2 + (size_t)npT * 1024;

    const float b1u = p.b1u[scol], b1f = p.b1f[scol], b1o = p.b1o[scol], b1c = p.b1c[scol];
    const float b2u = p.b2u[scol], b2f = p.b2f[scol], b2o = p.b2o[scol], b2c = p.b2c[scol];

    float m_reg[16];
    #pragma unroll
    for (int i = 0; i < 16; ++i) m_reg[i] = 0.f;

    Bar* barA = &p.bars[rt * 2 + 0];
    Bar* barB = &p.bars[rt * 2 + 1];

    auto slot = [&](int i) -> __bf16* { return p.ring + ((size_t)i << 19); };

    // kernel-start prologue for t=0 phase-1 (B then A order)
    {
        const __bf16* ax0 = p.xbf + ((size_t)(dof * NT) * NB + r0) * ND;
        const __bf16* ah0 = p.hInit + (size_t)r0 * NS + dof * ND;
        issueB(smem, wrow1, 0, row, kgb); issueB(smem, wrow1, 1, row, kgb); issueB(smem, wrow1, 2, row, kgb);
        issueA<4>(smem, ax0, ah0, 0, row, kgb); issueA<4>(smem, ax0, ah0, 1, row, kgb); issueA<4>(smem, ax0, ah0, 2, row, kgb);
    }

    for (int t = 0; t < NT; ++t) {
        const __bf16* ax  = p.xbf + ((size_t)(dof * NT + t) * NB + r0) * ND;
        __bf16* h1out = slot(2 * t);
        const __bf16* ah2 = slot(2 * t) + (size_t)r0 * NS;
        __bf16* h2out = slot(2 * t + 1);

        // ---------- phase 1: per-dof cell, K=512 = [x_t | h_own] ----------
        f32x4 acc[4][4];
        #pragma unroll
        for (int mI = 0; mI < 4; ++mI)
            #pragma unroll
            for (int g = 0; g < 4; ++g) acc[mI][g] = (f32x4){0.f, 0.f, 0.f, 0.f};

        const __bf16* ah1 = (t == 0 ? p.hInit : slot(2 * t - 1)) + (size_t)r0 * NS + dof * ND;
        gemm_core<8, 4>(smem, ax, ah1, wrow1, acc, lane, wr, ws, row, kgb);
        epilogue<false>(acc, m_reg, b1u, b1f, b1o, b1c, h1out, nullptr, rbase, scol, dof, colL);

        // barA: waves 1-3 pre-issue phase-2 B prologue (barrier-independent),
        // then each wave drains its own h-stores; wave0 issues B after poll.
        if (wv != 0) {
            issueB(smem, wrow2, 0, row, kgb); issueB(smem, wrow2, 1, row, kgb); issueB(smem, wrow2, 2, row, kgb);
            waitv_imm(12);
        } else {
            waitv_imm(0);
        }
        block_bar();
        if (tid == 0) arrive_poll(barA, 32, (unsigned)(t + 1));
        block_bar();
        if (wv == 0) {
            issueB(smem, wrow2, 0, row, kgb); issueB(smem, wrow2, 1, row, kgb); issueB(smem, wrow2, 2, row, kgb);
        }
        issueA<0>(smem, nullptr, ah2, 0, row, kgb);
        issueA<0>(smem, nullptr, ah2, 1, row, kgb);
        issueA<0>(smem, nullptr, ah2, 2, row, kgb);

        // ---------- phase 2: grid coupling, K=1024 = full h row ----------
        #pragma unroll
        for (int mI = 0; mI < 4; ++mI)
            #pragma unroll
            for (int g = 0; g < 4; ++g) acc[mI][g] = (f32x4){0.f, 0.f, 0.f, 0.f};

        gemm_core<16, 0>(smem, nullptr, ah2, wrow2, acc, lane, wr, ws, row, kgb);

        if (t + 1 < NT) {
            epilogue<false>(acc, m_reg, b2u, b2f, b2o, b2c, h2out, nullptr, rbase, scol, dof, colL);
            const __bf16* axn  = p.xbf + ((size_t)(dof * NT + t + 1) * NB + r0) * ND;
            const __bf16* ah1n = slot(2 * t + 1) + (size_t)r0 * NS + dof * ND;  // not read in pairs 0-2
            if (wv != 0) {   // full next-phase-1 prologue is barrier-independent (pairs 0-2 are x)
                issueB(smem, wrow1, 0, row, kgb); issueB(smem, wrow1, 1, row, kgb); issueB(smem, wrow1, 2, row, kgb);
                issueA<4>(smem, axn, ah1n, 0, row, kgb); issueA<4>(smem, axn, ah1n, 1, row, kgb); issueA<4>(smem, axn, ah1n, 2, row, kgb);
                waitv_imm(24);
            } else {
                waitv_imm(0);
            }
            block_bar();
            if (tid == 0) arrive_poll(barB, 32, (unsigned)(t + 1));
            block_bar();
            if (wv == 0) {
                issueB(smem, wrow1, 0, row, kgb); issueB(smem, wrow1, 1, row, kgb); issueB(smem, wrow1, 2, row, kgb);
                issueA<4>(smem, axn, ah1n, 0, row, kgb); issueA<4>(smem, axn, ah1n, 1, row, kgb); issueA<4>(smem, axn, ah1n, 2, row, kgb);
            }
        } else {
            epilogue<true>(acc, m_reg, b2u, b2f, b2o, b2c, nullptr, p.out, rbase, scol, dof, colL);
        }
    }
}

// ---- one-time prep: x[d][b][t][:] fp32 -> xbf[d][t][b][:] bf16 ----
__global__ __launch_bounds__(256)
void convert_x(const float* __restrict__ x, __bf16* __restrict__ xbf)
{
    const int id  = blockIdx.x * 256 + threadIdx.x;
    const int d0  = (id & 31) * 8;
    const int t   = (id >> 5) & 63;
    const int b   = (id >> 11) & 511;
    const int dof = id >> 20;
    const float* s = x + (((size_t)dof * NB + b) * NT + t) * ND + d0;
    const float4 v0 = *(const float4*)s;
    const float4 v1 = *(const float4*)(s + 4);
    bf16x8 o;
    o[0] = (__bf16)v0.x; o[1] = (__bf16)v0.y; o[2] = (__bf16)v0.z; o[3] = (__bf16)v0.w;
    o[4] = (__bf16)v1.x; o[5] = (__bf16)v1.y; o[6] = (__bf16)v1.z; o[7] = (__bf16)v1.w;
    *(bf16x8*)(xbf + (((size_t)dof * NT + t) * NB + b) * ND + d0) = o;
}

// ---- one-time prep: weights -> bf16 wT[n'][k], n' = dof*1024 + g*256 + col ----
__global__ __launch_bounds__(256)
void transpose_weights(const float* __restrict__ wu, const float* __restrict__ wf,
                       const float* __restrict__ wo, const float* __restrict__ wcp,
                       const float* __restrict__ gwu, const float* __restrict__ gwf,
                       const float* __restrict__ gwo, const float* __restrict__ gwc,
                       __bf16* __restrict__ wT1, __bf16* __restrict__ wT2)
{
    int id = blockIdx.x * 256 + threadIdx.x;
    const int C1 = 4096 * 64;
    int K, np, kc;
    const float *s0, *s1, *s2, *s3;
    __bf16* dst;
    if (id < C1) { K = 512;  np = id & 4095; kc = id >> 12; dst = wT1; s0 = wu;  s1 = wf;  s2 = wo;  s3 = wcp; }
    else { id -= C1; K = 1024; np = id & 4095; kc = id >> 12; dst = wT2; s0 = gwu; s1 = gwf; s2 = gwo; s3 = gwc; }
    const int dof = np >> 10, q = np & 1023, g = q >> 8, col = q & 255;
    const float* w = ((g == 0) ? s0 : (g == 1) ? s1 : (g == 2) ? s2 : s3)
                     + ((size_t)dof * K + kc * 8) * ND + col;
    bf16x8 o;
    #pragma unroll
    for (int j = 0; j < 8; ++j) o[j] = (__bf16)w[j * ND];
    *(bf16x8*)(dst + (size_t)np * K + kc * 8) = o;
}

extern "C" void kernel_launch(void* const* d_in, const int* in_sizes, int n_in,
                              void* d_out, int out_size, void* d_ws, size_t ws_size,
                              hipStream_t stream)
{
    const float* x   = (const float*)d_in[0];
    const float* wu  = (const float*)d_in[1];
    const float* wf  = (const float*)d_in[2];
    const float* wo  = (const float*)d_in[3];
    const float* wc  = (const float*)d_in[4];

    char* ws = (char*)d_ws;
    __bf16* wT1  = (__bf16*)ws;                        //   4 MB  [4096][512]
    __bf16* wT2  = (__bf16*)(ws + (4u  << 20));        //   8 MB  [4096][1024]
    __bf16* xbf  = (__bf16*)(ws + (12u << 20));        //  64 MB  [4][64][512][256]
    __bf16* hIn  = (__bf16*)(ws + (76u << 20));        //   1 MB  zeros
    Bar*    bars = (Bar*)  (ws + (78u << 20));         //   4 KB
    __bf16* ring = (__bf16*)(ws + (80u << 20));        // 128 MB  [NT*2][512][1024]

    convert_x<<<16384, 256, 0, stream>>>(x, xbf);
    transpose_weights<<<3072, 256, 0, stream>>>(
        wu, wf, wo, wc,
        (const float*)d_in[9], (const float*)d_in[10],
        (const float*)d_in[11], (const float*)d_in[12], wT1, wT2);
    // zero hInit + bars each call (deterministic across replays)
    hipMemsetAsync(ws + (76u << 20), 0, (2u << 20) + 4096, stream);

    Params p;
    p.xbf = xbf; p.wT1 = wT1; p.wT2 = wT2;
    p.b1u = (const float*)d_in[5];  p.b1f = (const float*)d_in[6];
    p.b1o = (const float*)d_in[7];  p.b1c = (const float*)d_in[8];
    p.b2u = (const float*)d_in[13]; p.b2f = (const float*)d_in[14];
    p.b2o = (const float*)d_in[15]; p.b2c = (const float*)d_in[16];
    p.hInit = hIn; p.ring = ring; p.out = (float*)d_out; p.bars = bars;

    lstm_persistent<<<dim3(GRID), dim3(256), 0, stream>>>(p);
}

// Round 10
// 2268.891 us; speedup vs baseline: 1.7445x; 1.1520x over previous
//
#include <hip/hip_runtime.h>
#include <math.h>

#define NDOF 4
#define NB   512
#define NT   64
#define ND   256
#define NS   1024           // NDOF*ND

// 128 blocks; work→block mapping is XCD-aware (see lstm_persistent body).
#define NRT  4
#define GRID 128

typedef __attribute__((ext_vector_type(8))) __bf16 bf16x8;
typedef __attribute__((ext_vector_type(4))) float  f32x4;

// cached global->LDS (weights, x, ring-h: ring slots are write-once -> cached
// reads coherent; no address is re-read after a remote write)
__device__ __forceinline__ void gll16(const void* g, void* l) {
    __builtin_amdgcn_global_load_lds(
        (const __attribute__((address_space(1))) unsigned int*)g,
        (__attribute__((address_space(3))) unsigned int*)l, 16, 0, 0);
}

__device__ __forceinline__ float sig_(float x) { return 1.0f / (1.0f + __expf(-x)); }
__device__ __forceinline__ float tanh_(float x) {
    float e = __expf(-2.0f * fabsf(x));
    float t = (1.0f - e) / (1.0f + e);
    return copysignf(t, x);
}

// h store: sc0 sc1 write-through to MALL (globally visible once vmcnt-retired)
__device__ __forceinline__ void store_h_dev(__bf16* p, float hv) {
    __bf16 hb = (__bf16)hv;
    unsigned v = (unsigned)__builtin_bit_cast(unsigned short, hb);
    asm volatile("global_store_short %0, %1, off sc0 sc1" :: "v"(p), "v"(v) : "memory");
}

__device__ __forceinline__ void waitv_imm(int n) {
    if (n >= 24)      asm volatile("s_waitcnt vmcnt(24)" ::: "memory");
    else if (n == 16) asm volatile("s_waitcnt vmcnt(16)" ::: "memory");
    else if (n == 12) asm volatile("s_waitcnt vmcnt(12)" ::: "memory");
    else if (n == 8)  asm volatile("s_waitcnt vmcnt(8)"  ::: "memory");
    else              asm volatile("s_waitcnt vmcnt(0)"  ::: "memory");
    __builtin_amdgcn_sched_barrier(0);
}

// raw block barrier: does NOT drain vmcnt (loads stay in flight across it).
__device__ __forceinline__ void block_bar() {
    __builtin_amdgcn_sched_barrier(0);
    asm volatile("s_waitcnt lgkmcnt(0)\n\ts_barrier" ::: "memory");
    __builtin_amdgcn_sched_barrier(0);
}

// coherent flag read: plain MALL load (no line ownership)
__device__ __forceinline__ unsigned gen_load(const unsigned* p) {
    unsigned v;
    asm volatile("global_load_dword %0, %1, off sc0 sc1\n\ts_waitcnt vmcnt(0)"
                 : "=v"(v) : "v"(p) : "memory");
    return v;
}

// -------- split arrive/poll group barriers --------
struct __align__(64) Bar { unsigned cnt; unsigned gen; unsigned pad[14]; };

__device__ __forceinline__ void arrive_only(Bar* b, unsigned n, unsigned e) {
    unsigned prev = __hip_atomic_fetch_add(&b->cnt, 1u, __ATOMIC_RELAXED, __HIP_MEMORY_SCOPE_AGENT);
    if (prev == e * n - 1u)
        __hip_atomic_fetch_add(&b->gen, 1u, __ATOMIC_RELAXED, __HIP_MEMORY_SCOPE_AGENT);
}
__device__ __forceinline__ void poll_only(Bar* b, unsigned e) {
    unsigned spins = 0;
    while (gen_load(&b->gen) < e) {
        __builtin_amdgcn_s_sleep(1);
        if (++spins > (1u << 17)) break;   // failsafe: fail loud, never hang
    }
}

struct Params {
    const __bf16* xbf;
    const __bf16* wT1;
    const __bf16* wT2;
    const float *b1u, *b1f, *b1o, *b1c;
    const float *b2u, *b2f, *b2o, *b2c;
    const __bf16* hInit;   // 1 MB zeros [512][1024]
    __bf16* ring;          // [NT*2] slots of [512][1024] bf16 (1 MB each)
    float*  out;
    Bar*    bars;          // [0..3]=bar32A[rt]; [4+g]=bar8A; [20+g]=bar8B (g=rt*4+dof)
};

// ---- pair staging. rot permutes the K order (pair p -> k ((p+rot)&mask)*64).
// LDS 16B-units: A 4-deep [0,4096), B 4-deep [4096,8192); buffer = pair&3.
__device__ __forceinline__ void issueB(bf16x8* smem, const __bf16* wrow,
                                       int pair, int rot, int mask, int row, int kgb) {
    const int bb = 4096 + (pair & 3) * 1024;
    const int k0 = ((pair + rot) & mask) * 64;
    #pragma unroll
    for (int i = 0; i < 4; ++i) {
        const int kg = kgb + 2 * i;
        gll16(wrow + k0 + kg * 8, &smem[bb + kg * 128 + row]);
    }
}
template<int XIT>
__device__ __forceinline__ void issueA(bf16x8* smem, const __bf16* ax,
                                       const __bf16* ah, int pair, int rot, int mask,
                                       int row, int kgb) {
    const int bb = (pair & 3) * 1024;
    const __bf16* base;
    if (XIT > 0 && pair < XIT) base = ax + (size_t)row * ND + pair * 64;   // x part (rot=0)
    else base = ah + (size_t)row * NS + (((pair + rot) & mask) * 64 - XIT * 64);
    #pragma unroll
    for (int i = 0; i < 4; ++i) {
        const int kg = kgb + 2 * i;
        gll16(base + kg * 8, &smem[bb + kg * 128 + row]);
    }
}

// ---- GEMM core. Pairs 0-2 pre-issued (order B0B1B2 A0A1A2). vmcnt table
// (verified for that order, 8 loads/pair): it0->8, it1->12, it==NIT-2->8,
// it==NIT-1->0, else 16. gateBar (if set) is polled at it==1, just before
// pair 4 is issued -- hides the group sync under pairs 0-3's compute.
template<int NIT, int XIT>
__device__ __forceinline__ void gemm_core(bf16x8* smem,
    const __bf16* ax, const __bf16* ah, const __bf16* wrow, int rot,
    Bar* gateBar, unsigned gateE,
    f32x4 (&acc)[4][4], int lane, int wr, int ws, int row, int kgb, int tid)
{
    #pragma unroll
    for (int it = 0; it < NIT; ++it) {
        waitv_imm(it == 0 ? 8 : it == 1 ? 12 :
                  it >= NIT - 1 ? 0 : it == NIT - 2 ? 8 : 16);
        block_bar();   // all waves' pair(it) landed; buffer (it+3)&3 free
        if (it == 1 && gateBar != nullptr) {
            if (tid == 0) poll_only(gateBar, gateE);
            block_bar();
        }
        if (it + 3 < NIT) {
            issueB(smem, wrow, it + 3, rot, NIT - 1, row, kgb);
            issueA<XIT>(smem, ax, ah, it + 3, rot, NIT - 1, row, kgb);
        }
        const int bb = (it & 3) * 1024;
        #pragma unroll
        for (int sub = 0; sub < 2; ++sub) {
            const int kq = sub * 4 + (lane >> 4);
            bf16x8 a[4], b[4];
            #pragma unroll
            for (int mI = 0; mI < 4; ++mI)
                a[mI] = smem[bb + kq * 128 + wr + mI * 16 + (lane & 15)];
            #pragma unroll
            for (int g = 0; g < 4; ++g)
                b[g] = smem[4096 + bb + kq * 128 + g * 32 + ws * 16 + (lane & 15)];
            #pragma unroll
            for (int mI = 0; mI < 4; ++mI)
                #pragma unroll
                for (int g = 0; g < 4; ++g)
                    acc[mI][g] = __builtin_amdgcn_mfma_f32_16x16x32_bf16(a[mI], b[g], acc[mI][g], 0, 0, 0);
        }
    }
}

// ---- in-lane LSTM epilogue (gate-major: gates live in acc[mI][0..3]) ----
template<bool LAST>
__device__ __forceinline__ void epilogue(const f32x4 (&acc)[4][4], float (&m_reg)[16],
    float bu, float bf_, float bo, float bc,
    __bf16* __restrict__ hout, float* __restrict__ out,
    int rbase, int scol, int dof, int colL)
{
    #pragma unroll
    for (int mI = 0; mI < 4; ++mI) {
        #pragma unroll
        for (int r = 0; r < 4; ++r) {
            const int row = rbase + mI * 16 + r;
            const float gu = sig_(acc[mI][0][r] + bu);
            const float gf = sig_(acc[mI][1][r] + bf_);
            const float go = sig_(acc[mI][2][r] + bo);
            const float gc = tanh_(acc[mI][3][r] + bc);
            float& m = m_reg[mI * 4 + r];
            m = gf * m + gu * gc;
            const float hv = tanh_(go * m);
            if (LAST) {
                const size_t oi = ((size_t)dof * NB + row) * ND + colL;
                out[oi] = hv;
                out[(size_t)NDOF * NB * ND + oi] = m;
            } else {
                store_h_dev(&hout[(size_t)row * NS + scol], hv);
            }
        }
    }
}

__global__ __launch_bounds__(256, 1)
void lstm_persistent(Params p)
{
    __shared__ bf16x8 smem[8192];   // 128 KB: A 4-deep, B 4-deep

    const int tid  = threadIdx.x;
    const int lane = tid & 63;
    const int wv   = tid >> 6;
    const int wr   = (wv >> 1) * 64;
    const int ws   = wv & 1;

    // ---- XCD-aware work map (dispatch assigns bid -> XCD bid%8) ----
    const int xcd   = blockIdx.x & 7;
    const int local = blockIdx.x >> 3;            // 0..15
    const int dof   = xcd & 3;
    const int rt    = ((xcd >> 2) << 1) | (local >> 3);   // 0..3
    const int c0    = (local & 7) * 32;
    const int r0    = rt * 128;
    const int grp   = rt * 4 + dof;               // 8-block group id

    const int row  = tid & 127;
    const int kgb  = (tid >> 7) & 1;

    const int colL = c0 + ws * 16 + (lane & 15);
    const int scol = dof * ND + colL;
    const int rbase = r0 + wr + (lane >> 4) * 4;

    const int rowT = tid & 127;
    const int npT  = dof * 1024 + (rowT >> 5) * 256 + c0 + (rowT & 31);
    const __bf16* wrow1 = p.wT1 + (size_t)npT * 512;
    const __bf16* wrow2 = p.wT2 + (size_t)npT * 1024;

    const float b1u = p.b1u[scol], b1f = p.b1f[scol], b1o = p.b1o[scol], b1c = p.b1c[scol];
    const float b2u = p.b2u[scol], b2f = p.b2f[scol], b2o = p.b2o[scol], b2c = p.b2c[scol];

    float m_reg[16];
    #pragma unroll
    for (int i = 0; i < 16; ++i) m_reg[i] = 0.f;

    Bar* bar32A = &p.bars[rt];
    Bar* bar8A  = &p.bars[4 + grp];
    Bar* bar8B  = &p.bars[20 + grp];
    const int rot2 = dof * 4;   // phase-2 K rotation: own-dof h1 cols first

    auto slot = [&](int i) -> __bf16* { return p.ring + ((size_t)i << 19); };

    // kernel-start prologue for t=0 phase-1 (B0 B1 B2 then A0 A1 A2)
    {
        const __bf16* ax0 = p.xbf + ((size_t)(dof * NT) * NB + r0) * ND;
        const __bf16* ah0 = p.hInit + (size_t)r0 * NS + dof * ND;
        issueB(smem, wrow1, 0, 0, 7, row, kgb); issueB(smem, wrow1, 1, 0, 7, row, kgb); issueB(smem, wrow1, 2, 0, 7, row, kgb);
        issueA<4>(smem, ax0, ah0, 0, 0, 7, row, kgb); issueA<4>(smem, ax0, ah0, 1, 0, 7, row, kgb); issueA<4>(smem, ax0, ah0, 2, 0, 7, row, kgb);
    }

    for (int t = 0; t < NT; ++t) {
        const __bf16* ax  = p.xbf + ((size_t)(dof * NT + t) * NB + r0) * ND;
        const __bf16* ah1 = (t == 0 ? p.hInit : slot(2 * t - 1)) + (size_t)r0 * NS + dof * ND;
        __bf16* h1out = slot(2 * t);
        const __bf16* ah2 = slot(2 * t) + (size_t)r0 * NS;
        __bf16* h2out = slot(2 * t + 1);

        // ---------- phase 1: per-dof cell, K=512 = [x_t | h_own] ----------
        // h pairs (4-7) gated at iter1 on bar8B >= t (own 8-block group).
        f32x4 acc[4][4];
        #pragma unroll
        for (int mI = 0; mI < 4; ++mI)
            #pragma unroll
            for (int g = 0; g < 4; ++g) acc[mI][g] = (f32x4){0.f, 0.f, 0.f, 0.f};

        gemm_core<8, 4>(smem, ax, ah1, wrow1, 0, bar8B, (unsigned)t,
                        acc, lane, wr, ws, row, kgb, tid);
        epilogue<false>(acc, m_reg, b1u, b1f, b1o, b1c, h1out, nullptr, rbase, scol, dof, colL);

        // transition: B2 prologue (indep) -> stores retired -> arrive both
        // barriers, poll only the OWN 8-block one -> own-dof A pairs.
        issueB(smem, wrow2, 0, rot2, 15, row, kgb);
        issueB(smem, wrow2, 1, rot2, 15, row, kgb);
        issueB(smem, wrow2, 2, rot2, 15, row, kgb);
        waitv_imm(12);            // 16 stores retired; 12 B loads in flight
        block_bar();
        if (tid == 0) {
            arrive_only(bar8A, 8, (unsigned)(t + 1));
            arrive_only(bar32A, 32, (unsigned)(t + 1));
            poll_only(bar8A, (unsigned)(t + 1));
        }
        block_bar();
        issueA<0>(smem, nullptr, ah2, 0, rot2, 15, row, kgb);
        issueA<0>(smem, nullptr, ah2, 1, rot2, 15, row, kgb);
        issueA<0>(smem, nullptr, ah2, 2, rot2, 15, row, kgb);

        // ---------- phase 2: grid coupling, K=1024 (rotated: own dof first).
        // Other-dof pairs (4+) gated at iter1 on bar32A >= t+1.
        #pragma unroll
        for (int mI = 0; mI < 4; ++mI)
            #pragma unroll
            for (int g = 0; g < 4; ++g) acc[mI][g] = (f32x4){0.f, 0.f, 0.f, 0.f};

        gemm_core<16, 0>(smem, nullptr, ah2, wrow2, rot2, bar32A, (unsigned)(t + 1),
                         acc, lane, wr, ws, row, kgb, tid);

        if (t + 1 < NT) {
            epilogue<false>(acc, m_reg, b2u, b2f, b2o, b2c, h2out, nullptr, rbase, scol, dof, colL);
            // next phase-1 prologue: all barrier-independent (B wT1 + A x(t+1))
            const __bf16* axn = p.xbf + ((size_t)(dof * NT + t + 1) * NB + r0) * ND;
            issueB(smem, wrow1, 0, 0, 7, row, kgb);
            issueB(smem, wrow1, 1, 0, 7, row, kgb);
            issueB(smem, wrow1, 2, 0, 7, row, kgb);
            issueA<4>(smem, axn, nullptr, 0, 0, 7, row, kgb);
            issueA<4>(smem, axn, nullptr, 1, 0, 7, row, kgb);
            issueA<4>(smem, axn, nullptr, 2, 0, 7, row, kgb);
            waitv_imm(24);        // 16 stores retired; 24 prologue loads in flight
            block_bar();
            if (tid == 0) arrive_only(bar8B, 8, (unsigned)(t + 1));
            // no poll here: next phase-1 gates at its iter1
        } else {
            epilogue<true>(acc, m_reg, b2u, b2f, b2o, b2c, nullptr, p.out, rbase, scol, dof, colL);
        }
    }
}

// ---- one-time prep: x[d][b][t][:] fp32 -> xbf[d][t][b][:] bf16 ----
__global__ __launch_bounds__(256)
void convert_x(const float* __restrict__ x, __bf16* __restrict__ xbf)
{
    const int id  = blockIdx.x * 256 + threadIdx.x;
    const int d0  = (id & 31) * 8;
    const int t   = (id >> 5) & 63;
    const int b   = (id >> 11) & 511;
    const int dof = id >> 20;
    const float* s = x + (((size_t)dof * NB + b) * NT + t) * ND + d0;
    const float4 v0 = *(const float4*)s;
    const float4 v1 = *(const float4*)(s + 4);
    bf16x8 o;
    o[0] = (__bf16)v0.x; o[1] = (__bf16)v0.y; o[2] = (__bf16)v0.z; o[3] = (__bf16)v0.w;
    o[4] = (__bf16)v1.x; o[5] = (__bf16)v1.y; o[6] = (__bf16)v1.z; o[7] = (__bf16)v1.w;
    *(bf16x8*)(xbf + (((size_t)dof * NT + t) * NB + b) * ND + d0) = o;
}

// ---- one-time prep: weights -> bf16 wT[n'][k], n' = dof*1024 + g*256 + col ----
__global__ __launch_bounds__(256)
void transpose_weights(const float* __restrict__ wu, const float* __restrict__ wf,
                       const float* __restrict__ wo, const float* __restrict__ wcp,
                       const float* __restrict__ gwu, const float* __restrict__ gwf,
                       const float* __restrict__ gwo, const float* __restrict__ gwc,
                       __bf16* __restrict__ wT1, __bf16* __restrict__ wT2)
{
    int id = blockIdx.x * 256 + threadIdx.x;
    const int C1 = 4096 * 64;
    int K, np, kc;
    const float *s0, *s1, *s2, *s3;
    __bf16* dst;
    if (id < C1) { K = 512;  np = id & 4095; kc = id >> 12; dst = wT1; s0 = wu;  s1 = wf;  s2 = wo;  s3 = wcp; }
    else { id -= C1; K = 1024; np = id & 4095; kc = id >> 12; dst = wT2; s0 = gwu; s1 = gwf; s2 = gwo; s3 = gwc; }
    const int dof = np >> 10, q = np & 1023, g = q >> 8, col = q & 255;
    const float* w = ((g == 0) ? s0 : (g == 1) ? s1 : (g == 2) ? s2 : s3)
                     + ((size_t)dof * K + kc * 8) * ND + col;
    bf16x8 o;
    #pragma unroll
    for (int j = 0; j < 8; ++j) o[j] = (__bf16)w[j * ND];
    *(bf16x8*)(dst + (size_t)np * K + kc * 8) = o;
}

extern "C" void kernel_launch(void* const* d_in, const int* in_sizes, int n_in,
                              void* d_out, int out_size, void* d_ws, size_t ws_size,
                              hipStream_t stream)
{
    const float* x   = (const float*)d_in[0];
    const float* wu  = (const float*)d_in[1];
    const float* wf  = (const float*)d_in[2];
    const float* wo  = (const float*)d_in[3];
    const float* wc  = (const float*)d_in[4];

    char* ws = (char*)d_ws;
    __bf16* wT1  = (__bf16*)ws;                        //   4 MB  [4096][512]
    __bf16* wT2  = (__bf16*)(ws + (4u  << 20));        //   8 MB  [4096][1024]
    __bf16* xbf  = (__bf16*)(ws + (12u << 20));        //  64 MB  [4][64][512][256]
    __bf16* hIn  = (__bf16*)(ws + (76u << 20));        //   1 MB  zeros
    Bar*    bars = (Bar*)  (ws + (78u << 20));         //   4 KB
    __bf16* ring = (__bf16*)(ws + (80u << 20));        // 128 MB  [NT*2][512][1024]

    convert_x<<<16384, 256, 0, stream>>>(x, xbf);
    transpose_weights<<<3072, 256, 0, stream>>>(
        wu, wf, wo, wc,
        (const float*)d_in[9], (const float*)d_in[10],
        (const float*)d_in[11], (const float*)d_in[12], wT1, wT2);
    // zero hInit + bars each call (deterministic across replays)
    hipMemsetAsync(ws + (76u << 20), 0, (2u << 20) + 4096, stream);

    Params p;
    p.xbf = xbf; p.wT1 = wT1; p.wT2 = wT2;
    p.b1u = (const float*)d_in[5];  p.b1f = (const float*)d_in[6];
    p.b1o = (const float*)d_in[7];  p.b1c = (const float*)d_in[8];
    p.b2u = (const float*)d_in[13]; p.b2f = (const float*)d_in[14];
    p.b2o = (const float*)d_in[15]; p.b2c = (const float*)d_in[16];
    p.hInit = hIn; p.ring = ring; p.out = (float*)d_out; p.bars = bars;

    lstm_persistent<<<dim3(GRID), dim3(256), 0, stream>>>(p);
}

// Round 11
// 2150.824 us; speedup vs baseline: 1.8402x; 1.0549x over previous
//
#include <hip/hip_runtime.h>
#include <math.h>

#define NDOF 4
#define NB   512
#define NT   64
#define ND   256
#define NS   1024           // NDOF*ND

// 128 blocks; work→block mapping is XCD-aware (see lstm_persistent body).
#define NRT  4
#define GRID 128

typedef __attribute__((ext_vector_type(8))) __bf16 bf16x8;
typedef __attribute__((ext_vector_type(4))) float  f32x4;

// cached global->LDS (weights, x, ring-h: ring slots are write-once -> cached
// reads coherent; no address is re-read after a remote write)
__device__ __forceinline__ void gll16(const void* g, void* l) {
    __builtin_amdgcn_global_load_lds(
        (const __attribute__((address_space(1))) unsigned int*)g,
        (__attribute__((address_space(3))) unsigned int*)l, 16, 0, 0);
}

__device__ __forceinline__ float sig_(float x) { return 1.0f / (1.0f + __expf(-x)); }
__device__ __forceinline__ float tanh_(float x) {
    float e = __expf(-2.0f * fabsf(x));
    float t = (1.0f - e) / (1.0f + e);
    return copysignf(t, x);
}

// coalesced coherent store: 16B write-through to MALL
__device__ __forceinline__ void store16_dev(__bf16* p, bf16x8 v) {
    asm volatile("global_store_dwordx4 %0, %1, off sc0 sc1" :: "v"(p), "v"(v) : "memory");
}

__device__ __forceinline__ void waitv_imm(int n) {
    if (n >= 24)      asm volatile("s_waitcnt vmcnt(24)" ::: "memory");
    else if (n == 16) asm volatile("s_waitcnt vmcnt(16)" ::: "memory");
    else if (n == 12) asm volatile("s_waitcnt vmcnt(12)" ::: "memory");
    else if (n == 8)  asm volatile("s_waitcnt vmcnt(8)"  ::: "memory");
    else              asm volatile("s_waitcnt vmcnt(0)"  ::: "memory");
    __builtin_amdgcn_sched_barrier(0);
}

// raw block barrier: does NOT drain vmcnt (loads stay in flight across it).
__device__ __forceinline__ void block_bar() {
    __builtin_amdgcn_sched_barrier(0);
    asm volatile("s_waitcnt lgkmcnt(0)\n\ts_barrier" ::: "memory");
    __builtin_amdgcn_sched_barrier(0);
}

// coherent flag read: plain MALL load (no line ownership)
__device__ __forceinline__ unsigned gen_load(const unsigned* p) {
    unsigned v;
    asm volatile("global_load_dword %0, %1, off sc0 sc1\n\ts_waitcnt vmcnt(0)"
                 : "=v"(v) : "v"(p) : "memory");
    return v;
}

// -------- split arrive/poll group barriers --------
struct __align__(64) Bar { unsigned cnt; unsigned gen; unsigned pad[14]; };

__device__ __forceinline__ void arrive_only(Bar* b, unsigned n, unsigned e) {
    unsigned prev = __hip_atomic_fetch_add(&b->cnt, 1u, __ATOMIC_RELAXED, __HIP_MEMORY_SCOPE_AGENT);
    if (prev == e * n - 1u)
        __hip_atomic_fetch_add(&b->gen, 1u, __ATOMIC_RELAXED, __HIP_MEMORY_SCOPE_AGENT);
}
__device__ __forceinline__ void poll_only(Bar* b, unsigned e) {
    unsigned spins = 0;
    while (gen_load(&b->gen) < e) {
        __builtin_amdgcn_s_sleep(1);
        if (++spins > (1u << 17)) break;   // failsafe: fail loud, never hang
    }
}

struct Params {
    const __bf16* xbf;
    const __bf16* wT1;
    const __bf16* wT2;
    const float *b1u, *b1f, *b1o, *b1c;
    const float *b2u, *b2f, *b2o, *b2c;
    const __bf16* hInit;   // 1 MB zeros [512][1024]
    __bf16* ring;          // [NT*2] slots of [512][1024] bf16 (1 MB each)
    float*  out;
    Bar*    bars;          // [0..3]=bar32A[rt]; [4+g]=bar8A; [20+g]=bar8B
};

// ---- pair staging. rot permutes the K order (pair p -> k ((p+rot)&mask)*64).
__device__ __forceinline__ void issueB(bf16x8* smem, const __bf16* wrow,
                                       int pair, int rot, int mask, int row, int kgb) {
    const int bb = 4096 + (pair & 3) * 1024;
    const int k0 = ((pair + rot) & mask) * 64;
    #pragma unroll
    for (int i = 0; i < 4; ++i) {
        const int kg = kgb + 2 * i;
        gll16(wrow + k0 + kg * 8, &smem[bb + kg * 128 + row]);
    }
}
template<int XIT>
__device__ __forceinline__ void issueA(bf16x8* smem, const __bf16* ax,
                                       const __bf16* ah, int pair, int rot, int mask,
                                       int row, int kgb) {
    const int bb = (pair & 3) * 1024;
    const __bf16* base;
    if (XIT > 0 && pair < XIT) base = ax + (size_t)row * ND + pair * 64;   // x part (rot=0)
    else base = ah + (size_t)row * NS + (((pair + rot) & mask) * 64 - XIT * 64);
    #pragma unroll
    for (int i = 0; i < 4; ++i) {
        const int kg = kgb + 2 * i;
        gll16(base + kg * 8, &smem[bb + kg * 128 + row]);
    }
}

// ---- GEMM core (unchanged from r10). Pairs 0-2 pre-issued (B0B1B2 A0A1A2).
template<int NIT, int XIT>
__device__ __forceinline__ void gemm_core(bf16x8* smem,
    const __bf16* ax, const __bf16* ah, const __bf16* wrow, int rot,
    Bar* gateBar, unsigned gateE,
    f32x4 (&acc)[4][4], int lane, int wr, int ws, int row, int kgb, int tid)
{
    #pragma unroll
    for (int it = 0; it < NIT; ++it) {
        waitv_imm(it == 0 ? 8 : it == 1 ? 12 :
                  it >= NIT - 1 ? 0 : it == NIT - 2 ? 8 : 16);
        block_bar();   // all waves' pair(it) landed; buffer (it+3)&3 free
        if (it == 1 && gateBar != nullptr) {
            if (tid == 0) poll_only(gateBar, gateE);
            block_bar();
        }
        if (it + 3 < NIT) {
            issueB(smem, wrow, it + 3, rot, NIT - 1, row, kgb);
            issueA<XIT>(smem, ax, ah, it + 3, rot, NIT - 1, row, kgb);
        }
        const int bb = (it & 3) * 1024;
        #pragma unroll
        for (int sub = 0; sub < 2; ++sub) {
            const int kq = sub * 4 + (lane >> 4);
            bf16x8 a[4], b[4];
            #pragma unroll
            for (int mI = 0; mI < 4; ++mI)
                a[mI] = smem[bb + kq * 128 + wr + mI * 16 + (lane & 15)];
            #pragma unroll
            for (int g = 0; g < 4; ++g)
                b[g] = smem[4096 + bb + kq * 128 + g * 32 + ws * 16 + (lane & 15)];
            #pragma unroll
            for (int mI = 0; mI < 4; ++mI)
                #pragma unroll
                for (int g = 0; g < 4; ++g)
                    acc[mI][g] = __builtin_amdgcn_mfma_f32_16x16x32_bf16(a[mI], b[g], acc[mI][g], 0, 0, 0);
        }
    }
}

// ---- LSTM epilogue: compute gates, update m_reg, stage h (bf16) into LDS ----
// staging tile [128 rows][32 cols], row stride 80 B (16B-aligned, bank-spread).
__device__ __forceinline__ void epi_stage(const f32x4 (&acc)[4][4], float (&m_reg)[16],
    float bu, float bf_, float bo, float bc,
    char* stg, int wrL, int colq)
{
    #pragma unroll
    for (int mI = 0; mI < 4; ++mI) {
        #pragma unroll
        for (int r = 0; r < 4; ++r) {
            const int rowL = wrL + mI * 16 + r;   // local row 0..127
            const float gu = sig_(acc[mI][0][r] + bu);
            const float gf = sig_(acc[mI][1][r] + bf_);
            const float go = sig_(acc[mI][2][r] + bo);
            const float gc = tanh_(acc[mI][3][r] + bc);
            float& m = m_reg[mI * 4 + r];
            m = gf * m + gu * gc;
            ((__bf16*)(stg + rowL * 80))[colq] = (__bf16)tanh_(go * m);
        }
    }
}

// coalesced flush of the staged 128x32 bf16 tile: 2 x 16B stores per thread,
// 64B-contiguous runs per row (vs r10's 16 scattered 2B stores per thread).
__device__ __forceinline__ void flush_h(char* stg, __bf16* hbase, int r0,
                                        int scolBase, int tid)
{
    #pragma unroll
    for (int k = 0; k < 2; ++k) {
        const int c = tid + 256 * k;          // 0..511
        const int rowL = c >> 2;
        const int off  = c & 3;               // 4 x 16B chunks per row
        bf16x8 v = *(bf16x8*)(stg + rowL * 80 + off * 16);
        store16_dev(hbase + (size_t)(r0 + rowL) * NS + scolBase + off * 8, v);
    }
}

// final-step epilogue: stage h,m as f32 in (idle) pipeline LDS, coalesced out.
__device__ __forceinline__ void epi_last(const f32x4 (&acc)[4][4], float (&m_reg)[16],
    float bu, float bf_, float bo, float bc,
    char* hs, char* ms, int wrL, int colq)
{
    #pragma unroll
    for (int mI = 0; mI < 4; ++mI) {
        #pragma unroll
        for (int r = 0; r < 4; ++r) {
            const int rowL = wrL + mI * 16 + r;
            const float gu = sig_(acc[mI][0][r] + bu);
            const float gf = sig_(acc[mI][1][r] + bf_);
            const float go = sig_(acc[mI][2][r] + bo);
            const float gc = tanh_(acc[mI][3][r] + bc);
            float& m = m_reg[mI * 4 + r];
            m = gf * m + gu * gc;
            ((float*)(hs + rowL * 144))[colq] = tanh_(go * m);
            ((float*)(ms + rowL * 144))[colq] = m;
        }
    }
}

__global__ __launch_bounds__(256, 1)
void lstm_persistent(Params p)
{
    __shared__ bf16x8 smem[8832];   // 128KB pipeline + 10KB h staging
    char* stg = (char*)&smem[8192]; // [128][80B] bf16 staging

    const int tid  = threadIdx.x;
    const int lane = tid & 63;
    const int wv   = tid >> 6;
    const int wr   = (wv >> 1) * 64;
    const int ws   = wv & 1;

    // ---- XCD-aware work map (dispatch assigns bid -> XCD bid%8) ----
    const int xcd   = blockIdx.x & 7;
    const int local = blockIdx.x >> 3;            // 0..15
    const int dof   = xcd & 3;
    const int rt    = ((xcd >> 2) << 1) | (local >> 3);   // 0..3
    const int c0    = (local & 7) * 32;
    const int r0    = rt * 128;
    const int grp   = rt * 4 + dof;

    const int row  = tid & 127;
    const int kgb  = (tid >> 7) & 1;

    const int colq = ws * 16 + (lane & 15);       // 0..31 (block-local col)
    const int scol = dof * ND + c0 + colq;
    const int scolBase = dof * ND + c0;
    const int wrL  = wr + (lane >> 4) * 4;        // local row base

    const int rowT = tid & 127;
    const int npT  = dof * 1024 + (rowT >> 5) * 256 + c0 + (rowT & 31);
    const __bf16* wrow1 = p.wT1 + (size_t)npT * 512;
    const __bf16* wrow2 = p.wT2 + (size_t)npT * 1024;

    const float b1u = p.b1u[scol], b1f = p.b1f[scol], b1o = p.b1o[scol], b1c = p.b1c[scol];
    const float b2u = p.b2u[scol], b2f = p.b2f[scol], b2o = p.b2o[scol], b2c = p.b2c[scol];

    float m_reg[16];
    #pragma unroll
    for (int i = 0; i < 16; ++i) m_reg[i] = 0.f;

    Bar* bar32A = &p.bars[rt];
    Bar* bar8A  = &p.bars[4 + grp];
    Bar* bar8B  = &p.bars[20 + grp];
    const int rot2 = dof * 4;   // phase-2 K rotation: own-dof h1 cols first

    auto slot = [&](int i) -> __bf16* { return p.ring + ((size_t)i << 19); };

    // kernel-start prologue for t=0 phase-1 (B0 B1 B2 then A0 A1 A2)
    {
        const __bf16* ax0 = p.xbf + ((size_t)(dof * NT) * NB + r0) * ND;
        const __bf16* ah0 = p.hInit + (size_t)r0 * NS + dof * ND;
        issueB(smem, wrow1, 0, 0, 7, row, kgb); issueB(smem, wrow1, 1, 0, 7, row, kgb); issueB(smem, wrow1, 2, 0, 7, row, kgb);
        issueA<4>(smem, ax0, ah0, 0, 0, 7, row, kgb); issueA<4>(smem, ax0, ah0, 1, 0, 7, row, kgb); issueA<4>(smem, ax0, ah0, 2, 0, 7, row, kgb);
    }

    for (int t = 0; t < NT; ++t) {
        const __bf16* ax  = p.xbf + ((size_t)(dof * NT + t) * NB + r0) * ND;
        const __bf16* ah1 = (t == 0 ? p.hInit : slot(2 * t - 1)) + (size_t)r0 * NS + dof * ND;
        __bf16* h1out = slot(2 * t);
        const __bf16* ah2 = slot(2 * t) + (size_t)r0 * NS;
        __bf16* h2out = slot(2 * t + 1);

        // ---------- phase 1: per-dof cell, K=512 = [x_t | h_own] ----------
        f32x4 acc[4][4];
        #pragma unroll
        for (int mI = 0; mI < 4; ++mI)
            #pragma unroll
            for (int g = 0; g < 4; ++g) acc[mI][g] = (f32x4){0.f, 0.f, 0.f, 0.f};

        gemm_core<8, 4>(smem, ax, ah1, wrow1, 0, bar8B, (unsigned)t,
                        acc, lane, wr, ws, row, kgb, tid);

        // ---- transition A (coalesced h1 store) ----
        epi_stage(acc, m_reg, b1u, b1f, b1o, b1c, stg, wrL, colq);
        block_bar();                      // staging visible block-wide
        flush_h(stg, h1out, r0, scolBase, tid);      // 2 coalesced stores (oldest)
        issueB(smem, wrow2, 0, rot2, 15, row, kgb);  // 12 B2-prologue loads
        issueB(smem, wrow2, 1, rot2, 15, row, kgb);
        issueB(smem, wrow2, 2, rot2, 15, row, kgb);
        waitv_imm(12);                    // retires the 2 stores, loads in flight
        block_bar();
        if (tid == 0) {
            arrive_only(bar8A, 8, (unsigned)(t + 1));
            arrive_only(bar32A, 32, (unsigned)(t + 1));
            poll_only(bar8A, (unsigned)(t + 1));
        }
        block_bar();
        issueA<0>(smem, nullptr, ah2, 0, rot2, 15, row, kgb);
        issueA<0>(smem, nullptr, ah2, 1, rot2, 15, row, kgb);
        issueA<0>(smem, nullptr, ah2, 2, rot2, 15, row, kgb);

        // ---------- phase 2: grid coupling, K=1024 (own dof first) ----------
        #pragma unroll
        for (int mI = 0; mI < 4; ++mI)
            #pragma unroll
            for (int g = 0; g < 4; ++g) acc[mI][g] = (f32x4){0.f, 0.f, 0.f, 0.f};

        gemm_core<16, 0>(smem, nullptr, ah2, wrow2, rot2, bar32A, (unsigned)(t + 1),
                         acc, lane, wr, ws, row, kgb, tid);

        if (t + 1 < NT) {
            // ---- transition B (coalesced h2 store) ----
            epi_stage(acc, m_reg, b2u, b2f, b2o, b2c, stg, wrL, colq);
            block_bar();
            flush_h(stg, h2out, r0, scolBase, tid);  // 2 stores (oldest)
            const __bf16* axn = p.xbf + ((size_t)(dof * NT + t + 1) * NB + r0) * ND;
            issueB(smem, wrow1, 0, 0, 7, row, kgb);
            issueB(smem, wrow1, 1, 0, 7, row, kgb);
            issueB(smem, wrow1, 2, 0, 7, row, kgb);
            issueA<4>(smem, axn, nullptr, 0, 0, 7, row, kgb);
            issueA<4>(smem, axn, nullptr, 1, 0, 7, row, kgb);
            issueA<4>(smem, axn, nullptr, 2, 0, 7, row, kgb);
            waitv_imm(24);                // retires the 2 stores; 24 loads in flight
            block_bar();
            if (tid == 0) arrive_only(bar8B, 8, (unsigned)(t + 1));
            // next phase-1 gates on bar8B at its iter 1
        } else {
            // ---- final epilogue: coalesced f32 h+m into d_out ----
            block_bar();                  // pipeline LDS now reusable
            char* hs = (char*)smem;           // [128][144B] f32 h
            char* ms = (char*)smem + 36864;   // [128][144B] f32 m
            epi_last(acc, m_reg, b2u, b2f, b2o, b2c, hs, ms, wrL, colq);
            block_bar();
            #pragma unroll
            for (int k = 0; k < 4; ++k) {
                const int c = tid + 256 * k;      // 0..1023
                const int rowL = c >> 3;
                const int off  = c & 7;           // 8 x 16B per 128B row
                const size_t gi = ((size_t)dof * NB + r0 + rowL) * ND + c0 + off * 4;
                *(f32x4*)(p.out + gi) = *(f32x4*)(hs + rowL * 144 + off * 16);
                *(f32x4*)(p.out + (size_t)NDOF * NB * ND + gi) = *(f32x4*)(ms + rowL * 144 + off * 16);
            }
        }
    }
}

// ---- one-time prep: x[d][b][t][:] fp32 -> xbf[d][t][b][:] bf16 ----
__global__ __launch_bounds__(256)
void convert_x(const float* __restrict__ x, __bf16* __restrict__ xbf)
{
    const int id  = blockIdx.x * 256 + threadIdx.x;
    const int d0  = (id & 31) * 8;
    const int t   = (id >> 5) & 63;
    const int b   = (id >> 11) & 511;
    const int dof = id >> 20;
    const float* s = x + (((size_t)dof * NB + b) * NT + t) * ND + d0;
    const float4 v0 = *(const float4*)s;
    const float4 v1 = *(const float4*)(s + 4);
    bf16x8 o;
    o[0] = (__bf16)v0.x; o[1] = (__bf16)v0.y; o[2] = (__bf16)v0.z; o[3] = (__bf16)v0.w;
    o[4] = (__bf16)v1.x; o[5] = (__bf16)v1.y; o[6] = (__bf16)v1.z; o[7] = (__bf16)v1.w;
    *(bf16x8*)(xbf + (((size_t)dof * NT + t) * NB + b) * ND + d0) = o;
}

// ---- one-time prep: weights -> bf16 wT[n'][k], n' = dof*1024 + g*256 + col ----
__global__ __launch_bounds__(256)
void transpose_weights(const float* __restrict__ wu, const float* __restrict__ wf,
                       const float* __restrict__ wo, const float* __restrict__ wcp,
                       const float* __restrict__ gwu, const float* __restrict__ gwf,
                       const float* __restrict__ gwo, const float* __restrict__ gwc,
                       __bf16* __restrict__ wT1, __bf16* __restrict__ wT2)
{
    int id = blockIdx.x * 256 + threadIdx.x;
    const int C1 = 4096 * 64;
    int K, np, kc;
    const float *s0, *s1, *s2, *s3;
    __bf16* dst;
    if (id < C1) { K = 512;  np = id & 4095; kc = id >> 12; dst = wT1; s0 = wu;  s1 = wf;  s2 = wo;  s3 = wcp; }
    else { id -= C1; K = 1024; np = id & 4095; kc = id >> 12; dst = wT2; s0 = gwu; s1 = gwf; s2 = gwo; s3 = gwc; }
    const int dof = np >> 10, q = np & 1023, g = q >> 8, col = q & 255;
    const float* w = ((g == 0) ? s0 : (g == 1) ? s1 : (g == 2) ? s2 : s3)
                     + ((size_t)dof * K + kc * 8) * ND + col;
    bf16x8 o;
    #pragma unroll
    for (int j = 0; j < 8; ++j) o[j] = (__bf16)w[j * ND];
    *(bf16x8*)(dst + (size_t)np * K + kc * 8) = o;
}

extern "C" void kernel_launch(void* const* d_in, const int* in_sizes, int n_in,
                              void* d_out, int out_size, void* d_ws, size_t ws_size,
                              hipStream_t stream)
{
    const float* x   = (const float*)d_in[0];
    const float* wu  = (const float*)d_in[1];
    const float* wf  = (const float*)d_in[2];
    const float* wo  = (const float*)d_in[3];
    const float* wc  = (const float*)d_in[4];

    char* ws = (char*)d_ws;
    __bf16* wT1  = (__bf16*)ws;                        //   4 MB  [4096][512]
    __bf16* wT2  = (__bf16*)(ws + (4u  << 20));        //   8 MB  [4096][1024]
    __bf16* xbf  = (__bf16*)(ws + (12u << 20));        //  64 MB  [4][64][512][256]
    __bf16* hIn  = (__bf16*)(ws + (76u << 20));        //   1 MB  zeros
    Bar*    bars = (Bar*)  (ws + (78u << 20));         //   4 KB
    __bf16* ring = (__bf16*)(ws + (80u << 20));        // 128 MB  [NT*2][512][1024]

    convert_x<<<16384, 256, 0, stream>>>(x, xbf);
    transpose_weights<<<3072, 256, 0, stream>>>(
        wu, wf, wo, wc,
        (const float*)d_in[9], (const float*)d_in[10],
        (const float*)d_in[11], (const float*)d_in[12], wT1, wT2);
    // zero hInit + bars each call (deterministic across replays)
    hipMemsetAsync(ws + (76u << 20), 0, (2u << 20) + 4096, stream);

    Params p;
    p.xbf = xbf; p.wT1 = wT1; p.wT2 = wT2;
    p.b1u = (const float*)d_in[5];  p.b1f = (const float*)d_in[6];
    p.b1o = (const float*)d_in[7];  p.b1c = (const float*)d_in[8];
    p.b2u = (const float*)d_in[13]; p.b2f = (const float*)d_in[14];
    p.b2o = (const float*)d_in[15]; p.b2c = (const float*)d_in[16];
    p.hInit = hIn; p.ring = ring; p.out = (float*)d_out; p.bars = bars;

    lstm_persistent<<<dim3(GRID), dim3(256), 0, stream>>>(p);
}